// Round 13
// baseline (330.646 us; speedup 1.0000x reference)
//
#include <hip/hip_runtime.h>
#include <hip/hip_fp16.h>
#include <cstdint>

#define NEG_SLOPE 0.2f
#define SM_EPS 1e-16f
#define BN_EPS 1e-5f

struct alignas(8)  half4v { __half2 lo, hi; };
struct alignas(16) half8v { __half2 h0, h1, h2, h3; };

__device__ __forceinline__ void fma8(float* acc, const half8v& g, float w) {
  float2 f0 = __half22float2(g.h0), f1 = __half22float2(g.h1);
  float2 f2 = __half22float2(g.h2), f3 = __half22float2(g.h3);
  acc[0] = fmaf(w, f0.x, acc[0]); acc[1] = fmaf(w, f0.y, acc[1]);
  acc[2] = fmaf(w, f1.x, acc[2]); acc[3] = fmaf(w, f1.y, acc[3]);
  acc[4] = fmaf(w, f2.x, acc[4]); acc[5] = fmaf(w, f2.y, acc[5]);
  acc[6] = fmaf(w, f3.x, acc[6]); acc[7] = fmaf(w, f3.y, acc[7]);
}

// ---------- GEMM + fused attention coefficients, 4 rows/thread, fp16 G out ----------
template <int INC, int OUTC, int H>
__global__ __launch_bounds__(256) void gemm_k(const float* __restrict__ A,
                                              const float* __restrict__ W,
                                              const float* __restrict__ asrc,
                                              const float* __restrict__ adst,
                                              __half* __restrict__ G,
                                              float* __restrict__ als,
                                              float* __restrict__ ald, int nrows) {
  constexpr int TPR  = OUTC / 4;
  constexpr int RS   = 256 / TPR;
  constexpr int ROWS = RS * 4;
  __shared__ float wl[INC * OUTC];
  __shared__ float hl[ROWS * INC];
  for (int i = threadIdx.x * 4; i < INC * OUTC; i += 1024)
    *(float4*)&wl[i] = *(const float4*)&W[i];
  int r  = threadIdx.x / TPR;
  int c0 = (threadIdx.x % TPR) * 4;
  float4 sv = *(const float4*)&asrc[c0];
  float4 dv = *(const float4*)&adst[c0];
  for (int base = blockIdx.x * ROWS; base < nrows; base += gridDim.x * ROWS) {
    __syncthreads();
    int limit = min(ROWS, nrows - base) * INC;
    for (int i = threadIdx.x * 4; i < limit; i += 1024)
      *(float4*)&hl[i] = *(const float4*)&A[(size_t)base * INC + i];
    __syncthreads();
    float acc[4][4];
#pragma unroll
    for (int q = 0; q < 4; q++)
#pragma unroll
      for (int c = 0; c < 4; c++) acc[q][c] = 0.f;
#pragma unroll 8
    for (int k = 0; k < INC; k++) {
      float4 wv = *(float4*)&wl[k * OUTC + c0];
#pragma unroll
      for (int q = 0; q < 4; q++) {
        float h = hl[(r + q * RS) * INC + k];
        acc[q][0] = fmaf(h, wv.x, acc[q][0]);
        acc[q][1] = fmaf(h, wv.y, acc[q][1]);
        acc[q][2] = fmaf(h, wv.z, acc[q][2]);
        acc[q][3] = fmaf(h, wv.w, acc[q][3]);
      }
    }
    float ps[4], pd[4];
#pragma unroll
    for (int q = 0; q < 4; q++) {
      int rq = base + r + q * RS;
      if (rq < nrows) {
        half4v hv;
        hv.lo = __floats2half2_rn(acc[q][0], acc[q][1]);
        hv.hi = __floats2half2_rn(acc[q][2], acc[q][3]);
        *(half4v*)&G[(size_t)rq * OUTC + c0] = hv;
      }
      ps[q] = acc[q][0] * sv.x + acc[q][1] * sv.y + acc[q][2] * sv.z + acc[q][3] * sv.w;
      pd[q] = acc[q][0] * dv.x + acc[q][1] * dv.y + acc[q][2] * dv.z + acc[q][3] * dv.w;
    }
#pragma unroll
    for (int o = 1; o < 16; o <<= 1) {
#pragma unroll
      for (int q = 0; q < 4; q++) {
        ps[q] += __shfl_xor(ps[q], o);
        pd[q] += __shfl_xor(pd[q], o);
      }
    }
    if ((threadIdx.x & 15) == 0) {
      int head = c0 >> 6;
#pragma unroll
      for (int q = 0; q < 4; q++) {
        int rq = base + r + q * RS;
        if (rq < nrows) {
          als[(size_t)rq * H + head] = ps[q];
          ald[(size_t)rq * H + head] = pd[q];
        }
      }
    }
  }
}

// ---------- CSR build (XCD-local scatter) ----------
__global__ __launch_bounds__(256) void deg_k(const int* __restrict__ dst, int E_,
                                             int n, int* __restrict__ deg) {
  int g   = blockIdx.x & 7;
  int npg = (n + 7) / 8;
  int n0  = g * npg;
  int n1  = min(n0 + npg, n);
  int bg  = blockIdx.x >> 3;
  int nbg = gridDim.x >> 3;
  int ET  = E_ + n;
  for (int e = bg * 256 + threadIdx.x; e < ET; e += nbg * 256) {
    int dN = (e < E_) ? dst[e] : (e - E_);
    if (dN >= n0 && dN < n1) atomicAdd(&deg[dN], 1);
  }
}

__global__ __launch_bounds__(1024) void scan1_k(const int* __restrict__ deg,
                                                int* __restrict__ incl,
                                                int* __restrict__ bsum, int n) {
  __shared__ int sm[1024];
  int i = blockIdx.x * 1024 + threadIdx.x;
  int v = (i < n) ? deg[i] : 0;
  sm[threadIdx.x] = v;
  __syncthreads();
#pragma unroll
  for (int o = 1; o < 1024; o <<= 1) {
    int t = (threadIdx.x >= o) ? sm[threadIdx.x - o] : 0;
    __syncthreads();
    sm[threadIdx.x] += t;
    __syncthreads();
  }
  if (i < n) incl[i] = sm[threadIdx.x];
  if (threadIdx.x == 1023) bsum[blockIdx.x] = sm[1023];
}

__global__ void scan2_k(int* __restrict__ bsum, int nb) {
  int lane = threadIdx.x;
  int v = (lane < nb) ? bsum[lane] : 0;
#pragma unroll
  for (int o = 1; o < 64; o <<= 1) {
    int t = __shfl_up(v, o);
    if (lane >= o) v += t;
  }
  if (lane < nb) bsum[lane] = v;
}

__global__ void scan3_k(const int* __restrict__ incl, const int* __restrict__ bsum,
                        const int* __restrict__ deg, int* __restrict__ rowptr,
                        int* __restrict__ cursor, int n) {
  int i = blockIdx.x * blockDim.x + threadIdx.x;
  if (i < n) {
    int blk = i >> 10;
    int off = blk ? bsum[blk - 1] : 0;
    int r = incl[i] + off;
    rowptr[i + 1] = r;
    cursor[i] = r - deg[i];
  }
  if (i == 0) rowptr[0] = 0;
}

__global__ __launch_bounds__(256) void csr_fill_k(const int* __restrict__ src,
                                                  const int* __restrict__ dst, int E_,
                                                  int n, int* __restrict__ cursor,
                                                  uint16_t* __restrict__ csr_src) {
  int g   = blockIdx.x & 7;
  int npg = (n + 7) / 8;
  int n0  = g * npg;
  int n1  = min(n0 + npg, n);
  int bg  = blockIdx.x >> 3;
  int nbg = gridDim.x >> 3;
  int ET  = E_ + n;
  for (int e = bg * 256 + threadIdx.x; e < ET; e += nbg * 256) {
    int dN = (e < E_) ? dst[e] : (e - E_);
    if (dN >= n0 && dN < n1) {
      int sN  = (e < E_) ? src[e] : dN;
      int pos = atomicAdd(&cursor[dN], 1);
      csr_src[pos] = (uint16_t)sN;
    }
  }
}

// canonicalize: in-place rank-permutation sort of each dst segment by src id.
__global__ __launch_bounds__(256) void csr_canon_k(const int* __restrict__ rowptr,
                                                   uint16_t* __restrict__ csr, int n) {
  int l   = threadIdx.x & 31;
  int grp = (blockIdx.x * blockDim.x + threadIdx.x) >> 5;
  int ng  = (gridDim.x * blockDim.x) >> 5;
  for (int node = grp; node < n; node += ng) {
    int beg = rowptr[node];
    int deg = rowptr[node + 1] - beg;
    if (deg <= 1) continue;
    if (deg <= 128) {
      int iters = (deg + 31) >> 5;
      uint16_t v[4];
      int      rk[4];
#pragma unroll
      for (int m = 0; m < 4; m++) {
        if (m >= iters) break;
        int  i   = l + m * 32;
        bool act = i < deg;
        uint16_t vi = act ? csr[beg + i] : (uint16_t)0;
        int rank = 0;
        for (int j = 0; j < deg; j++) {
          uint16_t vj = csr[beg + j];
          rank += (int)((vj < vi) | ((vj == vi) & (j < i)));
        }
        v[m]  = vi;
        rk[m] = act ? rank : -1;
      }
#pragma unroll
      for (int m = 0; m < 4; m++) {
        if (m >= iters) break;
        if (rk[m] >= 0) csr[beg + rk[m]] = v[m];
      }
    } else if (l == 0) {
      for (int i = beg + 1; i < beg + deg; ++i) {
        uint16_t vv = csr[i];
        int j = i - 1;
        while (j >= beg && csr[j] > vv) { csr[j + 1] = csr[j]; --j; }
        csr[j + 1] = vv;
      }
    }
  }
}

// ---------- fused GAT aggregation (H=2): 4 nodes per group, setup/gather split ----------
__global__ __launch_bounds__(256) void gat_agg2_k(
    const int* __restrict__ rowptr, const uint16_t* __restrict__ csr_src,
    const float* __restrict__ als, const float* __restrict__ ald,
    const __half* __restrict__ G, const float* __restrict__ bias,
    const float* __restrict__ gamma, const float* __restrict__ beta,
    const float* __restrict__ mean, const float* __restrict__ var,
    float* __restrict__ out, int n) {
  int l   = threadIdx.x & 31;
  int grp = (blockIdx.x * blockDim.x + threadIdx.x) >> 5;
  int ehi = l >> 4;
  int sub = l & 15;
  int cc  = sub * 8;
  bool hh = sub >= 8;
  int node0 = grp * 4;
  if (node0 >= n) return;

  // ---- phase 1: setup for 4 nodes (overlapped miss chains) ----
  int   begq[4], degq[4], slq[4];
  float a0q[4], a1q[4];
  float adx[4], ady[4];
#pragma unroll
  for (int q = 0; q < 4; q++) {
    int nd = node0 + q;
    begq[q] = 0; degq[q] = 0; slq[q] = 0; a0q[q] = 0.f; a1q[q] = 0.f;
    adx[q] = 0.f; ady[q] = 0.f;
    if (nd < n) {
      begq[q] = rowptr[nd];
      degq[q] = rowptr[nd + 1] - begq[q];
      float2 adp = *(const float2*)&ald[(size_t)nd * 2];
      adx[q] = adp.x; ady[q] = adp.y;
      if (degq[q] <= 32 && l < degq[q]) slq[q] = csr_src[begq[q] + l];
    }
  }
#pragma unroll
  for (int q = 0; q < 4; q++) {
    if (node0 + q >= n || degq[q] > 32) continue;
    float p0 = 0.f, p1 = 0.f;
    if (l < degq[q]) {
      float2 ap = *(const float2*)&als[(size_t)slq[q] * 2];
      float v0 = ap.x + adx[q], v1 = ap.y + ady[q];
      v0 = v0 > 0.f ? v0 : NEG_SLOPE * v0;
      v1 = v1 > 0.f ? v1 : NEG_SLOPE * v1;
      p0 = __expf(v0); p1 = __expf(v1);
    }
    float s0 = p0, s1 = p1;
#pragma unroll
    for (int o = 1; o < 32; o <<= 1) {
      s0 += __shfl_xor(s0, o, 32);
      s1 += __shfl_xor(s1, o, 32);
    }
    a0q[q] = p0 / (s0 + SM_EPS);
    a1q[q] = p1 / (s1 + SM_EPS);
  }

  // ---- phase 2: gather + epilogue per node (math identical to round 12) ----
#pragma unroll
  for (int q = 0; q < 4; q++) {
    int nd = node0 + q;
    if (nd >= n) continue;
    int   beg = begq[q], deg = degq[q];
    float accP[8], accQ[8];
#pragma unroll
    for (int k = 0; k < 8; k++) { accP[k] = 0.f; accQ[k] = 0.f; }
    if (deg <= 32) {
      int   sl_ = slq[q];
      float a0 = a0q[q], a1 = a1q[q];
      for (int i = 0; i < deg; i += 8) {
        int e0 = i + ehi, e1 = i + 2 + ehi, e2 = i + 4 + ehi, e3 = i + 6 + ehi;
        int sA = __shfl(sl_, e0, 32);
        int sB = __shfl(sl_, e1, 32);
        int sC = __shfl(sl_, e2, 32);
        int sD = __shfl(sl_, e3, 32);
        float wA0 = __shfl(a0, e0, 32), wA1 = __shfl(a1, e0, 32);
        float wB0 = __shfl(a0, e1, 32), wB1 = __shfl(a1, e1, 32);
        float wC0 = __shfl(a0, e2, 32), wC1 = __shfl(a1, e2, 32);
        float wD0 = __shfl(a0, e3, 32), wD1 = __shfl(a1, e3, 32);
        float wA = hh ? wA1 : wA0, wB = hh ? wB1 : wB0;
        float wC = hh ? wC1 : wC0, wD = hh ? wD1 : wD0;
        half8v gA = *(const half8v*)&G[(size_t)sA * 128 + cc];
        half8v gB = *(const half8v*)&G[(size_t)sB * 128 + cc];
        half8v gC = *(const half8v*)&G[(size_t)sC * 128 + cc];
        half8v gD = *(const half8v*)&G[(size_t)sD * 128 + cc];
        fma8(accP, gA, wA);
        fma8(accQ, gB, wB);
        fma8(accP, gC, wC);
        fma8(accQ, gD, wD);
      }
    } else {
      float adpx = adx[q], adpy = ady[q];
      float s0 = 0.f, s1 = 0.f;
      for (int i = l; i < deg; i += 32) {
        int s = csr_src[beg + i];
        float2 ap = *(const float2*)&als[(size_t)s * 2];
        float v0 = ap.x + adpx; v0 = v0 > 0.f ? v0 : NEG_SLOPE * v0;
        float v1 = ap.y + adpy; v1 = v1 > 0.f ? v1 : NEG_SLOPE * v1;
        s0 += __expf(v0); s1 += __expf(v1);
      }
#pragma unroll
      for (int o = 1; o < 32; o <<= 1) {
        s0 += __shfl_xor(s0, o, 32);
        s1 += __shfl_xor(s1, o, 32);
      }
      float inv0 = 1.f / (s0 + SM_EPS);
      float inv1 = 1.f / (s1 + SM_EPS);
      for (int i = 0; i < deg; i += 2) {
        int  e   = i + ehi;
        bool act = e < deg;
        int  sE  = 0;
        float w  = 0.f;
        if (act) {
          sE = csr_src[beg + e];
          float2 ap = *(const float2*)&als[(size_t)sE * 2];
          float v0 = ap.x + adpx; v0 = v0 > 0.f ? v0 : NEG_SLOPE * v0;
          float v1 = ap.y + adpy; v1 = v1 > 0.f ? v1 : NEG_SLOPE * v1;
          w = hh ? (__expf(v1) * inv1) : (__expf(v0) * inv0);
        }
        half8v g = *(const half8v*)&G[(size_t)sE * 128 + cc];
        fma8(accP, g, w);
      }
    }
    float o8[8];
#pragma unroll
    for (int k = 0; k < 8; k++) {
      o8[k] = accP[k] + accQ[k];
      o8[k] += __shfl_xor(o8[k], 16, 32);
    }
    if (l < 16) {
      float4 bv0 = *(const float4*)&bias[cc],  bv1 = *(const float4*)&bias[cc + 4];
      float4 mv0 = *(const float4*)&mean[cc],  mv1 = *(const float4*)&mean[cc + 4];
      float4 vv0 = *(const float4*)&var[cc],   vv1 = *(const float4*)&var[cc + 4];
      float4 gv0 = *(const float4*)&gamma[cc], gv1 = *(const float4*)&gamma[cc + 4];
      float4 tv0 = *(const float4*)&beta[cc],  tv1 = *(const float4*)&beta[cc + 4];
      float4 u0, u1;
      u0.x = fmaxf((o8[0] + bv0.x - mv0.x) * rsqrtf(vv0.x + BN_EPS) * gv0.x + tv0.x, 0.f);
      u0.y = fmaxf((o8[1] + bv0.y - mv0.y) * rsqrtf(vv0.y + BN_EPS) * gv0.y + tv0.y, 0.f);
      u0.z = fmaxf((o8[2] + bv0.z - mv0.z) * rsqrtf(vv0.z + BN_EPS) * gv0.z + tv0.z, 0.f);
      u0.w = fmaxf((o8[3] + bv0.w - mv0.w) * rsqrtf(vv0.w + BN_EPS) * gv0.w + tv0.w, 0.f);
      u1.x = fmaxf((o8[4] + bv1.x - mv1.x) * rsqrtf(vv1.x + BN_EPS) * gv1.x + tv1.x, 0.f);
      u1.y = fmaxf((o8[5] + bv1.y - mv1.y) * rsqrtf(vv1.y + BN_EPS) * gv1.y + tv1.y, 0.f);
      u1.z = fmaxf((o8[6] + bv1.z - mv1.z) * rsqrtf(vv1.z + BN_EPS) * gv1.z + tv1.z, 0.f);
      u1.w = fmaxf((o8[7] + bv1.w - mv1.w) * rsqrtf(vv1.w + BN_EPS) * gv1.w + tv1.w, 0.f);
      *(float4*)&out[(size_t)nd * 128 + cc]     = u0;
      *(float4*)&out[(size_t)nd * 128 + cc + 4] = u1;
    }
  }
}

// ---------- GAT aggregation (H=1): 4 nodes per group, setup/gather split ----------
__global__ __launch_bounds__(256) void gat_agg1_k(
    const int* __restrict__ rowptr, const uint16_t* __restrict__ csr_src,
    const float* __restrict__ als, const float* __restrict__ ald,
    const __half* __restrict__ G, const float* __restrict__ bias,
    float* __restrict__ out, int n) {
  int l   = threadIdx.x & 31;
  int grp = (blockIdx.x * blockDim.x + threadIdx.x) >> 5;
  int e8  = l >> 3;
  int sub = l & 7;
  int cc  = sub * 8;
  int node0 = grp * 4;
  if (node0 >= n) return;

  int   begq[4], degq[4], slq[4];
  float a0q[4], adq[4];
#pragma unroll
  for (int q = 0; q < 4; q++) {
    int nd = node0 + q;
    begq[q] = 0; degq[q] = 0; slq[q] = 0; a0q[q] = 0.f; adq[q] = 0.f;
    if (nd < n) {
      begq[q] = rowptr[nd];
      degq[q] = rowptr[nd + 1] - begq[q];
      adq[q]  = ald[nd];
      if (degq[q] <= 32 && l < degq[q]) slq[q] = csr_src[begq[q] + l];
    }
  }
#pragma unroll
  for (int q = 0; q < 4; q++) {
    if (node0 + q >= n || degq[q] > 32) continue;
    float p0 = 0.f;
    if (l < degq[q]) {
      float v0 = als[slq[q]] + adq[q];
      v0 = v0 > 0.f ? v0 : NEG_SLOPE * v0;
      p0 = __expf(v0);
    }
    float s0 = p0;
#pragma unroll
    for (int o = 1; o < 32; o <<= 1) s0 += __shfl_xor(s0, o, 32);
    a0q[q] = p0 / (s0 + SM_EPS);
  }

#pragma unroll
  for (int q = 0; q < 4; q++) {
    int nd = node0 + q;
    if (nd >= n) continue;
    int beg = begq[q], deg = degq[q];
    float accP[8], accQ[8];
#pragma unroll
    for (int k = 0; k < 8; k++) { accP[k] = 0.f; accQ[k] = 0.f; }
    if (deg <= 32) {
      int   sl_ = slq[q];
      float a0  = a0q[q];
      for (int i = 0; i < deg; i += 16) {
        int e0 = i + e8, e1 = i + 4 + e8, e2 = i + 8 + e8, e3 = i + 12 + e8;
        int sA = __shfl(sl_, e0, 32);
        int sB = __shfl(sl_, e1, 32);
        int sC = __shfl(sl_, e2, 32);
        int sD = __shfl(sl_, e3, 32);
        float wA = __shfl(a0, e0, 32);
        float wB = __shfl(a0, e1, 32);
        float wC = __shfl(a0, e2, 32);
        float wD = __shfl(a0, e3, 32);
        half8v gA = *(const half8v*)&G[(size_t)sA * 64 + cc];
        half8v gB = *(const half8v*)&G[(size_t)sB * 64 + cc];
        half8v gC = *(const half8v*)&G[(size_t)sC * 64 + cc];
        half8v gD = *(const half8v*)&G[(size_t)sD * 64 + cc];
        fma8(accP, gA, wA);
        fma8(accQ, gB, wB);
        fma8(accP, gC, wC);
        fma8(accQ, gD, wD);
      }
    } else {
      float ad0 = adq[q];
      float s0 = 0.f;
      for (int i = l; i < deg; i += 32) {
        int s = csr_src[beg + i];
        float v0 = als[s] + ad0; v0 = v0 > 0.f ? v0 : NEG_SLOPE * v0;
        s0 += __expf(v0);
      }
#pragma unroll
      for (int o = 1; o < 32; o <<= 1) s0 += __shfl_xor(s0, o, 32);
      float inv0 = 1.f / (s0 + SM_EPS);
      for (int i = 0; i < deg; i += 4) {
        int  e   = i + e8;
        bool act = e < deg;
        int  sE  = 0;
        float w  = 0.f;
        if (act) {
          sE = csr_src[beg + e];
          float v0 = als[sE] + ad0; v0 = v0 > 0.f ? v0 : NEG_SLOPE * v0;
          w = __expf(v0) * inv0;
        }
        half8v g = *(const half8v*)&G[(size_t)sE * 64 + cc];
        fma8(accP, g, w);
      }
    }
    float o8[8];
#pragma unroll
    for (int k = 0; k < 8; k++) {
      o8[k] = accP[k] + accQ[k];
      o8[k] += __shfl_xor(o8[k], 8, 32);
      o8[k] += __shfl_xor(o8[k], 16, 32);
    }
    if (l < 8) {
      float4 bv0 = *(const float4*)&bias[cc], bv1 = *(const float4*)&bias[cc + 4];
      float4 u0 = make_float4(o8[0] + bv0.x, o8[1] + bv0.y, o8[2] + bv0.z, o8[3] + bv0.w);
      float4 u1 = make_float4(o8[4] + bv1.x, o8[5] + bv1.y, o8[6] + bv1.z, o8[7] + bv1.w);
      *(float4*)&out[(size_t)nd * 64 + cc]     = u0;
      *(float4*)&out[(size_t)nd * 64 + cc + 4] = u1;
    }
  }
}

// =======================================================================
extern "C" void kernel_launch(void* const* d_in, const int* in_sizes, int n_in,
                              void* d_out, int out_size, void* d_ws, size_t ws_size,
                              hipStream_t stream) {
  const float* x   = (const float*)d_in[0];
  const int*   ei  = (const int*)d_in[1];
  const float* W0  = (const float*)d_in[2];
  const float* as0 = (const float*)d_in[3];
  const float* ad0 = (const float*)d_in[4];
  const float* b0  = (const float*)d_in[5];
  const float* gm0 = (const float*)d_in[6];
  const float* bt0 = (const float*)d_in[7];
  const float* mu0 = (const float*)d_in[8];
  const float* vr0 = (const float*)d_in[9];
  const float* W1  = (const float*)d_in[10];
  const float* as1 = (const float*)d_in[11];
  const float* ad1 = (const float*)d_in[12];
  const float* b1  = (const float*)d_in[13];
  const float* gm1 = (const float*)d_in[14];
  const float* bt1 = (const float*)d_in[15];
  const float* mu1 = (const float*)d_in[16];
  const float* vr1 = (const float*)d_in[17];
  const float* W2  = (const float*)d_in[18];
  const float* as2 = (const float*)d_in[19];
  const float* ad2 = (const float*)d_in[20];
  const float* b2  = (const float*)d_in[21];

  int N  = in_sizes[0] / 128;
  int E  = in_sizes[1] / 2;
  int ET = E + N;
  const int* srcp = ei;
  const int* dstp = ei + E;

  char* w = (char*)d_ws;
  auto carve = [&](size_t bytes) {
    void* p = (void*)w;
    w += (bytes + 255) & ~(size_t)255;
    return p;
  };
  __half*   G      = (__half*)carve((size_t)N * 128 * 2);
  float*    Hb     = (float*)carve((size_t)N * 128 * 4);
  float*    ALS    = (float*)carve((size_t)N * 2 * 4);
  float*    ALD    = (float*)carve((size_t)N * 2 * 4);
  int*      DEG    = (int*)carve((size_t)N * 4);
  int*      INCL   = (int*)carve((size_t)N * 4);
  int*      BSUM   = (int*)carve((size_t)64 * 4);
  int*      ROWPTR = (int*)carve((size_t)(N + 1) * 4);
  int*      CURSOR = (int*)carve((size_t)N * 4);
  uint16_t* CSRSRC = (uint16_t*)carve((size_t)ET * 2);

  int cgrid = (N + 7) / 8;     // canon: 1 node per 32-lane group
  int agrid = (N + 31) / 32;   // agg: 4 nodes per group, 8 groups per block
  int nblk  = (N + 1023) / 1024;

  // ---- CSR build (graph shared by all 3 layers) ----
  hipMemsetAsync(DEG, 0, (size_t)N * 4, stream);
  deg_k<<<2048, 256, 0, stream>>>(dstp, E, N, DEG);
  scan1_k<<<nblk, 1024, 0, stream>>>(DEG, INCL, BSUM, N);
  scan2_k<<<1, 64, 0, stream>>>(BSUM, nblk);
  scan3_k<<<(N + 255) / 256, 256, 0, stream>>>(INCL, BSUM, DEG, ROWPTR, CURSOR, N);
  csr_fill_k<<<2048, 256, 0, stream>>>(srcp, dstp, E, N, CURSOR, CSRSRC);
  csr_canon_k<<<cgrid, 256, 0, stream>>>(ROWPTR, CSRSRC, N);

  // ---------------- layer 0 ----------------
  gemm_k<128, 128, 2><<<512, 256, 0, stream>>>(x, W0, as0, ad0, G, ALS, ALD, N);
  gat_agg2_k<<<agrid, 256, 0, stream>>>(ROWPTR, CSRSRC, ALS, ALD, G, b0, gm0, bt0,
                                        mu0, vr0, Hb, N);
  // ---------------- layer 1 ----------------
  gemm_k<128, 128, 2><<<512, 256, 0, stream>>>(Hb, W1, as1, ad1, G, ALS, ALD, N);
  gat_agg2_k<<<agrid, 256, 0, stream>>>(ROWPTR, CSRSRC, ALS, ALD, G, b1, gm1, bt1,
                                        mu1, vr1, Hb, N);
  // ---------------- layer 2 ----------------
  gemm_k<128, 64, 1><<<512, 256, 0, stream>>>(Hb, W2, as2, ad2, G, ALS, ALD, N);
  gat_agg1_k<<<agrid, 256, 0, stream>>>(ROWPTR, CSRSRC, ALS, ALD, G, b2,
                                        (float*)d_out, N);
}

// Round 14
// 318.807 us; speedup vs baseline: 1.0371x; 1.0371x over previous
//
#include <hip/hip_runtime.h>
#include <hip/hip_fp16.h>
#include <cstdint>

#define NEG_SLOPE 0.2f
#define SM_EPS 1e-16f
#define BN_EPS 1e-5f

struct alignas(8)  half4v { __half2 lo, hi; };
struct alignas(16) half8v { __half2 h0, h1, h2, h3; };

__device__ __forceinline__ void fma8(float* acc, const half8v& g, float w) {
  float2 f0 = __half22float2(g.h0), f1 = __half22float2(g.h1);
  float2 f2 = __half22float2(g.h2), f3 = __half22float2(g.h3);
  acc[0] = fmaf(w, f0.x, acc[0]); acc[1] = fmaf(w, f0.y, acc[1]);
  acc[2] = fmaf(w, f1.x, acc[2]); acc[3] = fmaf(w, f1.y, acc[3]);
  acc[4] = fmaf(w, f2.x, acc[4]); acc[5] = fmaf(w, f2.y, acc[5]);
  acc[6] = fmaf(w, f3.x, acc[6]); acc[7] = fmaf(w, f3.y, acc[7]);
}

// ---------- GEMM + fused attention coefficients, 4 rows/thread, fp16 G out ----------
template <int INC, int OUTC, int H>
__global__ __launch_bounds__(256) void gemm_k(const float* __restrict__ A,
                                              const float* __restrict__ W,
                                              const float* __restrict__ asrc,
                                              const float* __restrict__ adst,
                                              __half* __restrict__ G,
                                              float* __restrict__ als,
                                              float* __restrict__ ald, int nrows) {
  constexpr int TPR  = OUTC / 4;
  constexpr int RS   = 256 / TPR;
  constexpr int ROWS = RS * 4;
  __shared__ float wl[INC * OUTC];
  __shared__ float hl[ROWS * INC];
  for (int i = threadIdx.x * 4; i < INC * OUTC; i += 1024)
    *(float4*)&wl[i] = *(const float4*)&W[i];
  int r  = threadIdx.x / TPR;
  int c0 = (threadIdx.x % TPR) * 4;
  float4 sv = *(const float4*)&asrc[c0];
  float4 dv = *(const float4*)&adst[c0];
  for (int base = blockIdx.x * ROWS; base < nrows; base += gridDim.x * ROWS) {
    __syncthreads();
    int limit = min(ROWS, nrows - base) * INC;
    for (int i = threadIdx.x * 4; i < limit; i += 1024)
      *(float4*)&hl[i] = *(const float4*)&A[(size_t)base * INC + i];
    __syncthreads();
    float acc[4][4];
#pragma unroll
    for (int q = 0; q < 4; q++)
#pragma unroll
      for (int c = 0; c < 4; c++) acc[q][c] = 0.f;
#pragma unroll 8
    for (int k = 0; k < INC; k++) {
      float4 wv = *(float4*)&wl[k * OUTC + c0];
#pragma unroll
      for (int q = 0; q < 4; q++) {
        float h = hl[(r + q * RS) * INC + k];
        acc[q][0] = fmaf(h, wv.x, acc[q][0]);
        acc[q][1] = fmaf(h, wv.y, acc[q][1]);
        acc[q][2] = fmaf(h, wv.z, acc[q][2]);
        acc[q][3] = fmaf(h, wv.w, acc[q][3]);
      }
    }
    float ps[4], pd[4];
#pragma unroll
    for (int q = 0; q < 4; q++) {
      int rq = base + r + q * RS;
      if (rq < nrows) {
        half4v hv;
        hv.lo = __floats2half2_rn(acc[q][0], acc[q][1]);
        hv.hi = __floats2half2_rn(acc[q][2], acc[q][3]);
        *(half4v*)&G[(size_t)rq * OUTC + c0] = hv;
      }
      ps[q] = acc[q][0] * sv.x + acc[q][1] * sv.y + acc[q][2] * sv.z + acc[q][3] * sv.w;
      pd[q] = acc[q][0] * dv.x + acc[q][1] * dv.y + acc[q][2] * dv.z + acc[q][3] * dv.w;
    }
#pragma unroll
    for (int o = 1; o < 16; o <<= 1) {
#pragma unroll
      for (int q = 0; q < 4; q++) {
        ps[q] += __shfl_xor(ps[q], o);
        pd[q] += __shfl_xor(pd[q], o);
      }
    }
    if ((threadIdx.x & 15) == 0) {
      int head = c0 >> 6;
#pragma unroll
      for (int q = 0; q < 4; q++) {
        int rq = base + r + q * RS;
        if (rq < nrows) {
          als[(size_t)rq * H + head] = ps[q];
          ald[(size_t)rq * H + head] = pd[q];
        }
      }
    }
  }
}

// ---------- CSR build (XCD-local scatter) ----------
__global__ __launch_bounds__(256) void deg_k(const int* __restrict__ dst, int E_,
                                             int n, int* __restrict__ deg) {
  int g   = blockIdx.x & 7;
  int npg = (n + 7) / 8;
  int n0  = g * npg;
  int n1  = min(n0 + npg, n);
  int bg  = blockIdx.x >> 3;
  int nbg = gridDim.x >> 3;
  int ET  = E_ + n;
  for (int e = bg * 256 + threadIdx.x; e < ET; e += nbg * 256) {
    int dN = (e < E_) ? dst[e] : (e - E_);
    if (dN >= n0 && dN < n1) atomicAdd(&deg[dN], 1);
  }
}

__global__ __launch_bounds__(1024) void scan1_k(const int* __restrict__ deg,
                                                int* __restrict__ incl,
                                                int* __restrict__ bsum, int n) {
  __shared__ int sm[1024];
  int i = blockIdx.x * 1024 + threadIdx.x;
  int v = (i < n) ? deg[i] : 0;
  sm[threadIdx.x] = v;
  __syncthreads();
#pragma unroll
  for (int o = 1; o < 1024; o <<= 1) {
    int t = (threadIdx.x >= o) ? sm[threadIdx.x - o] : 0;
    __syncthreads();
    sm[threadIdx.x] += t;
    __syncthreads();
  }
  if (i < n) incl[i] = sm[threadIdx.x];
  if (threadIdx.x == 1023) bsum[blockIdx.x] = sm[1023];
}

__global__ void scan2_k(int* __restrict__ bsum, int nb) {
  int lane = threadIdx.x;
  int v = (lane < nb) ? bsum[lane] : 0;
#pragma unroll
  for (int o = 1; o < 64; o <<= 1) {
    int t = __shfl_up(v, o);
    if (lane >= o) v += t;
  }
  if (lane < nb) bsum[lane] = v;
}

__global__ void scan3_k(const int* __restrict__ incl, const int* __restrict__ bsum,
                        const int* __restrict__ deg, int* __restrict__ rowptr,
                        int* __restrict__ cursor, int n) {
  int i = blockIdx.x * blockDim.x + threadIdx.x;
  if (i < n) {
    int blk = i >> 10;
    int off = blk ? bsum[blk - 1] : 0;
    int r = incl[i] + off;
    rowptr[i + 1] = r;
    cursor[i] = r - deg[i];
  }
  if (i == 0) rowptr[0] = 0;
}

__global__ __launch_bounds__(256) void csr_fill_k(const int* __restrict__ src,
                                                  const int* __restrict__ dst, int E_,
                                                  int n, int* __restrict__ cursor,
                                                  uint16_t* __restrict__ csr_src) {
  int g   = blockIdx.x & 7;
  int npg = (n + 7) / 8;
  int n0  = g * npg;
  int n1  = min(n0 + npg, n);
  int bg  = blockIdx.x >> 3;
  int nbg = gridDim.x >> 3;
  int ET  = E_ + n;
  for (int e = bg * 256 + threadIdx.x; e < ET; e += nbg * 256) {
    int dN = (e < E_) ? dst[e] : (e - E_);
    if (dN >= n0 && dN < n1) {
      int sN  = (e < E_) ? src[e] : dN;
      int pos = atomicAdd(&cursor[dN], 1);
      csr_src[pos] = (uint16_t)sN;
    }
  }
}

// canonicalize: in-place rank-permutation sort of each dst segment by src id.
__global__ __launch_bounds__(256) void csr_canon_k(const int* __restrict__ rowptr,
                                                   uint16_t* __restrict__ csr, int n) {
  int l   = threadIdx.x & 31;
  int grp = (blockIdx.x * blockDim.x + threadIdx.x) >> 5;
  int ng  = (gridDim.x * blockDim.x) >> 5;
  for (int node = grp; node < n; node += ng) {
    int beg = rowptr[node];
    int deg = rowptr[node + 1] - beg;
    if (deg <= 1) continue;
    if (deg <= 128) {
      int iters = (deg + 31) >> 5;
      uint16_t v[4];
      int      rk[4];
#pragma unroll
      for (int m = 0; m < 4; m++) {
        if (m >= iters) break;
        int  i   = l + m * 32;
        bool act = i < deg;
        uint16_t vi = act ? csr[beg + i] : (uint16_t)0;
        int rank = 0;
        for (int j = 0; j < deg; j++) {
          uint16_t vj = csr[beg + j];
          rank += (int)((vj < vi) | ((vj == vi) & (j < i)));
        }
        v[m]  = vi;
        rk[m] = act ? rank : -1;
      }
#pragma unroll
      for (int m = 0; m < 4; m++) {
        if (m >= iters) break;
        if (rk[m] >= 0) csr[beg + rk[m]] = v[m];
      }
    } else if (l == 0) {
      for (int i = beg + 1; i < beg + deg; ++i) {
        uint16_t vv = csr[i];
        int j = i - 1;
        while (j >= beg && csr[j] > vv) { csr[j + 1] = csr[j]; --j; }
        csr[j + 1] = vv;
      }
    }
  }
}

// ---------- fused GAT aggregation (H=2): one node per wave64 ----------
// 64 lanes = 4 edge-slots x 16 row-lanes -> one load fetches 4 G rows (1 KB),
// unroll x4 keeps 16 edges (4 KB) in flight per wave. Softmax in lanes 0..31
// (deg<=32); width-64 shuffles broadcast indices/weights (sources < 32).
__global__ __launch_bounds__(256) void gat_agg2_k(
    const int* __restrict__ rowptr, const uint16_t* __restrict__ csr_src,
    const float* __restrict__ als, const float* __restrict__ ald,
    const __half* __restrict__ G, const float* __restrict__ bias,
    const float* __restrict__ gamma, const float* __restrict__ beta,
    const float* __restrict__ mean, const float* __restrict__ var,
    float* __restrict__ out, int n) {
  int l   = threadIdx.x & 63;
  int wv  = (blockIdx.x * blockDim.x + threadIdx.x) >> 6;
  int nw  = (gridDim.x * blockDim.x) >> 6;
  int e4  = l >> 4;        // edge slot 0..3
  int sub = l & 15;        // 16 lanes cover one 128-ch fp16 row
  int cc  = sub * 8;
  bool hh = sub >= 8;
  for (int node = wv; node < n; node += nw) {
    int beg = rowptr[node];
    int deg = rowptr[node + 1] - beg;
    float2 adp = *(const float2*)&ald[(size_t)node * 2];
    float accP[8], accQ[8];
#pragma unroll
    for (int k = 0; k < 8; k++) { accP[k] = 0.f; accQ[k] = 0.f; }
    if (deg <= 32) {
      int sl_ = 0;
      float p0 = 0.f, p1 = 0.f;
      if (l < deg) {                 // only lanes < 32 qualify
        sl_ = csr_src[beg + l];
        float2 ap = *(const float2*)&als[(size_t)sl_ * 2];
        float v0 = ap.x + adp.x, v1 = ap.y + adp.y;
        v0 = v0 > 0.f ? v0 : NEG_SLOPE * v0;
        v1 = v1 > 0.f ? v1 : NEG_SLOPE * v1;
        p0 = __expf(v0); p1 = __expf(v1);
      }
      float s0 = p0, s1 = p1;
#pragma unroll
      for (int o = 1; o < 32; o <<= 1) {   // valid within lanes 0..31
        s0 += __shfl_xor(s0, o, 32);
        s1 += __shfl_xor(s1, o, 32);
      }
      float a0 = p0 / (s0 + SM_EPS);   // lanes >= deg: a0 = a1 = 0
      float a1 = p1 / (s1 + SM_EPS);
      for (int i = 0; i < deg; i += 16) {
        int eA = i + e4, eB = i + 4 + e4, eC = i + 8 + e4, eD = i + 12 + e4;
        int sA = __shfl(sl_, eA);
        int sB = __shfl(sl_, eB);
        int sC = __shfl(sl_, eC);
        int sD = __shfl(sl_, eD);
        float wA0 = __shfl(a0, eA), wA1 = __shfl(a1, eA);
        float wB0 = __shfl(a0, eB), wB1 = __shfl(a1, eB);
        float wC0 = __shfl(a0, eC), wC1 = __shfl(a1, eC);
        float wD0 = __shfl(a0, eD), wD1 = __shfl(a1, eD);
        float wA = hh ? wA1 : wA0, wB = hh ? wB1 : wB0;
        float wC = hh ? wC1 : wC0, wD = hh ? wD1 : wD0;
        half8v gA = *(const half8v*)&G[(size_t)sA * 128 + cc];
        half8v gB = *(const half8v*)&G[(size_t)sB * 128 + cc];
        half8v gC = *(const half8v*)&G[(size_t)sC * 128 + cc];
        half8v gD = *(const half8v*)&G[(size_t)sD * 128 + cc];
        fma8(accP, gA, wA);
        fma8(accQ, gB, wB);
        fma8(accP, gC, wC);
        fma8(accQ, gD, wD);
      }
    } else {
      float s0 = 0.f, s1 = 0.f;
      for (int i = l; i < deg; i += 64) {
        int s = csr_src[beg + i];
        float2 ap = *(const float2*)&als[(size_t)s * 2];
        float v0 = ap.x + adp.x; v0 = v0 > 0.f ? v0 : NEG_SLOPE * v0;
        float v1 = ap.y + adp.y; v1 = v1 > 0.f ? v1 : NEG_SLOPE * v1;
        s0 += __expf(v0); s1 += __expf(v1);
      }
#pragma unroll
      for (int o = 1; o < 64; o <<= 1) {
        s0 += __shfl_xor(s0, o);
        s1 += __shfl_xor(s1, o);
      }
      float inv0 = 1.f / (s0 + SM_EPS);
      float inv1 = 1.f / (s1 + SM_EPS);
      for (int i = 0; i < deg; i += 4) {
        int  e   = i + e4;
        bool act = e < deg;
        int  sE  = 0;
        float w  = 0.f;
        if (act) {
          sE = csr_src[beg + e];
          float2 ap = *(const float2*)&als[(size_t)sE * 2];
          float v0 = ap.x + adp.x; v0 = v0 > 0.f ? v0 : NEG_SLOPE * v0;
          float v1 = ap.y + adp.y; v1 = v1 > 0.f ? v1 : NEG_SLOPE * v1;
          w = hh ? (__expf(v1) * inv1) : (__expf(v0) * inv0);
        }
        half8v g = *(const half8v*)&G[(size_t)sE * 128 + cc];
        fma8(accP, g, w);
      }
    }
    float o8[8];
#pragma unroll
    for (int k = 0; k < 8; k++) {
      o8[k] = accP[k] + accQ[k];
      o8[k] += __shfl_xor(o8[k], 16);
      o8[k] += __shfl_xor(o8[k], 32);
    }
    if (l < 16) {
      float4 bv0 = *(const float4*)&bias[cc],  bv1 = *(const float4*)&bias[cc + 4];
      float4 mv0 = *(const float4*)&mean[cc],  mv1 = *(const float4*)&mean[cc + 4];
      float4 vv0 = *(const float4*)&var[cc],   vv1 = *(const float4*)&var[cc + 4];
      float4 gv0 = *(const float4*)&gamma[cc], gv1 = *(const float4*)&gamma[cc + 4];
      float4 tv0 = *(const float4*)&beta[cc],  tv1 = *(const float4*)&beta[cc + 4];
      float4 u0, u1;
      u0.x = fmaxf((o8[0] + bv0.x - mv0.x) * rsqrtf(vv0.x + BN_EPS) * gv0.x + tv0.x, 0.f);
      u0.y = fmaxf((o8[1] + bv0.y - mv0.y) * rsqrtf(vv0.y + BN_EPS) * gv0.y + tv0.y, 0.f);
      u0.z = fmaxf((o8[2] + bv0.z - mv0.z) * rsqrtf(vv0.z + BN_EPS) * gv0.z + tv0.z, 0.f);
      u0.w = fmaxf((o8[3] + bv0.w - mv0.w) * rsqrtf(vv0.w + BN_EPS) * gv0.w + tv0.w, 0.f);
      u1.x = fmaxf((o8[4] + bv1.x - mv1.x) * rsqrtf(vv1.x + BN_EPS) * gv1.x + tv1.x, 0.f);
      u1.y = fmaxf((o8[5] + bv1.y - mv1.y) * rsqrtf(vv1.y + BN_EPS) * gv1.y + tv1.y, 0.f);
      u1.z = fmaxf((o8[6] + bv1.z - mv1.z) * rsqrtf(vv1.z + BN_EPS) * gv1.z + tv1.z, 0.f);
      u1.w = fmaxf((o8[7] + bv1.w - mv1.w) * rsqrtf(vv1.w + BN_EPS) * gv1.w + tv1.w, 0.f);
      *(float4*)&out[(size_t)node * 128 + cc]     = u0;
      *(float4*)&out[(size_t)node * 128 + cc + 4] = u1;
    }
  }
}

// ---------- GAT aggregation (H=1): one node per wave64, 8 rows per load ----------
__global__ __launch_bounds__(256) void gat_agg1_k(
    const int* __restrict__ rowptr, const uint16_t* __restrict__ csr_src,
    const float* __restrict__ als, const float* __restrict__ ald,
    const __half* __restrict__ G, const float* __restrict__ bias,
    float* __restrict__ out, int n) {
  int l   = threadIdx.x & 63;
  int wv  = (blockIdx.x * blockDim.x + threadIdx.x) >> 6;
  int nw  = (gridDim.x * blockDim.x) >> 6;
  int e8  = l >> 3;        // edge slot 0..7
  int sub = l & 7;         // 8 lanes cover one 64-ch fp16 row
  int cc  = sub * 8;
  for (int node = wv; node < n; node += nw) {
    int beg = rowptr[node];
    int deg = rowptr[node + 1] - beg;
    float ad0 = ald[node];
    float accP[8], accQ[8];
#pragma unroll
    for (int k = 0; k < 8; k++) { accP[k] = 0.f; accQ[k] = 0.f; }
    if (deg <= 32) {
      int sl_ = 0;
      float p0 = 0.f;
      if (l < deg) {
        sl_ = csr_src[beg + l];
        float v0 = als[sl_] + ad0;
        v0 = v0 > 0.f ? v0 : NEG_SLOPE * v0;
        p0 = __expf(v0);
      }
      float s0 = p0;
#pragma unroll
      for (int o = 1; o < 32; o <<= 1) s0 += __shfl_xor(s0, o, 32);
      float a0 = p0 / (s0 + SM_EPS);
      for (int i = 0; i < deg; i += 16) {
        int eA = i + e8, eB = i + 8 + e8;
        int sA = __shfl(sl_, eA);
        int sB = __shfl(sl_, eB);
        float wA = __shfl(a0, eA);
        float wB = __shfl(a0, eB);
        half8v gA = *(const half8v*)&G[(size_t)sA * 64 + cc];
        half8v gB = *(const half8v*)&G[(size_t)sB * 64 + cc];
        fma8(accP, gA, wA);
        fma8(accQ, gB, wB);
      }
    } else {
      float s0 = 0.f;
      for (int i = l; i < deg; i += 64) {
        int s = csr_src[beg + i];
        float v0 = als[s] + ad0; v0 = v0 > 0.f ? v0 : NEG_SLOPE * v0;
        s0 += __expf(v0);
      }
#pragma unroll
      for (int o = 1; o < 64; o <<= 1) s0 += __shfl_xor(s0, o);
      float inv0 = 1.f / (s0 + SM_EPS);
      for (int i = 0; i < deg; i += 8) {
        int  e   = i + e8;
        bool act = e < deg;
        int  sE  = 0;
        float w  = 0.f;
        if (act) {
          sE = csr_src[beg + e];
          float v0 = als[sE] + ad0; v0 = v0 > 0.f ? v0 : NEG_SLOPE * v0;
          w = __expf(v0) * inv0;
        }
        half8v g = *(const half8v*)&G[(size_t)sE * 64 + cc];
        fma8(accP, g, w);
      }
    }
    float o8[8];
#pragma unroll
    for (int k = 0; k < 8; k++) {
      o8[k] = accP[k] + accQ[k];
      o8[k] += __shfl_xor(o8[k], 8);
      o8[k] += __shfl_xor(o8[k], 16);
      o8[k] += __shfl_xor(o8[k], 32);
    }
    if (l < 8) {
      float4 bv0 = *(const float4*)&bias[cc], bv1 = *(const float4*)&bias[cc + 4];
      float4 u0 = make_float4(o8[0] + bv0.x, o8[1] + bv0.y, o8[2] + bv0.z, o8[3] + bv0.w);
      float4 u1 = make_float4(o8[4] + bv1.x, o8[5] + bv1.y, o8[6] + bv1.z, o8[7] + bv1.w);
      *(float4*)&out[(size_t)node * 64 + cc]     = u0;
      *(float4*)&out[(size_t)node * 64 + cc + 4] = u1;
    }
  }
}

// =======================================================================
extern "C" void kernel_launch(void* const* d_in, const int* in_sizes, int n_in,
                              void* d_out, int out_size, void* d_ws, size_t ws_size,
                              hipStream_t stream) {
  const float* x   = (const float*)d_in[0];
  const int*   ei  = (const int*)d_in[1];
  const float* W0  = (const float*)d_in[2];
  const float* as0 = (const float*)d_in[3];
  const float* ad0 = (const float*)d_in[4];
  const float* b0  = (const float*)d_in[5];
  const float* gm0 = (const float*)d_in[6];
  const float* bt0 = (const float*)d_in[7];
  const float* mu0 = (const float*)d_in[8];
  const float* vr0 = (const float*)d_in[9];
  const float* W1  = (const float*)d_in[10];
  const float* as1 = (const float*)d_in[11];
  const float* ad1 = (const float*)d_in[12];
  const float* b1  = (const float*)d_in[13];
  const float* gm1 = (const float*)d_in[14];
  const float* bt1 = (const float*)d_in[15];
  const float* mu1 = (const float*)d_in[16];
  const float* vr1 = (const float*)d_in[17];
  const float* W2  = (const float*)d_in[18];
  const float* as2 = (const float*)d_in[19];
  const float* ad2 = (const float*)d_in[20];
  const float* b2  = (const float*)d_in[21];

  int N  = in_sizes[0] / 128;
  int E  = in_sizes[1] / 2;
  int ET = E + N;
  const int* srcp = ei;
  const int* dstp = ei + E;

  char* w = (char*)d_ws;
  auto carve = [&](size_t bytes) {
    void* p = (void*)w;
    w += (bytes + 255) & ~(size_t)255;
    return p;
  };
  __half*   G      = (__half*)carve((size_t)N * 128 * 2);
  float*    Hb     = (float*)carve((size_t)N * 128 * 4);
  float*    ALS    = (float*)carve((size_t)N * 2 * 4);
  float*    ALD    = (float*)carve((size_t)N * 2 * 4);
  int*      DEG    = (int*)carve((size_t)N * 4);
  int*      INCL   = (int*)carve((size_t)N * 4);
  int*      BSUM   = (int*)carve((size_t)64 * 4);
  int*      ROWPTR = (int*)carve((size_t)(N + 1) * 4);
  int*      CURSOR = (int*)carve((size_t)N * 4);
  uint16_t* CSRSRC = (uint16_t*)carve((size_t)ET * 2);

  int cgrid = (N + 7) / 8;   // canon: 1 node per 32-lane group
  int agrid = (N + 3) / 4;   // agg: 1 node per wave64, 4 waves/block
  int nblk  = (N + 1023) / 1024;

  // ---- CSR build (graph shared by all 3 layers) ----
  hipMemsetAsync(DEG, 0, (size_t)N * 4, stream);
  deg_k<<<2048, 256, 0, stream>>>(dstp, E, N, DEG);
  scan1_k<<<nblk, 1024, 0, stream>>>(DEG, INCL, BSUM, N);
  scan2_k<<<1, 64, 0, stream>>>(BSUM, nblk);
  scan3_k<<<(N + 255) / 256, 256, 0, stream>>>(INCL, BSUM, DEG, ROWPTR, CURSOR, N);
  csr_fill_k<<<2048, 256, 0, stream>>>(srcp, dstp, E, N, CURSOR, CSRSRC);
  csr_canon_k<<<cgrid, 256, 0, stream>>>(ROWPTR, CSRSRC, N);

  // ---------------- layer 0 ----------------
  gemm_k<128, 128, 2><<<512, 256, 0, stream>>>(x, W0, as0, ad0, G, ALS, ALD, N);
  gat_agg2_k<<<agrid, 256, 0, stream>>>(ROWPTR, CSRSRC, ALS, ALD, G, b0, gm0, bt0,
                                        mu0, vr0, Hb, N);
  // ---------------- layer 1 ----------------
  gemm_k<128, 128, 2><<<512, 256, 0, stream>>>(Hb, W1, as1, ad1, G, ALS, ALD, N);
  gat_agg2_k<<<agrid, 256, 0, stream>>>(ROWPTR, CSRSRC, ALS, ALD, G, b1, gm1, bt1,
                                        mu1, vr1, Hb, N);
  // ---------------- layer 2 ----------------
  gemm_k<128, 64, 1><<<512, 256, 0, stream>>>(Hb, W2, as2, ad2, G, ALS, ALD, N);
  gat_agg1_k<<<agrid, 256, 0, stream>>>(ROWPTR, CSRSRC, ALS, ALD, G, b2,
                                        (float*)d_out, N);
}

// Round 15
// 318.247 us; speedup vs baseline: 1.0390x; 1.0018x over previous
//
#include <hip/hip_runtime.h>
#include <hip/hip_fp16.h>
#include <cstdint>

#define NEG_SLOPE 0.2f
#define SM_EPS 1e-16f
#define BN_EPS 1e-5f

struct alignas(8)  half4v { __half2 lo, hi; };
struct alignas(16) half8v { __half2 h0, h1, h2, h3; };

__device__ __forceinline__ void fma8(float* acc, const half8v& g, float w) {
  float2 f0 = __half22float2(g.h0), f1 = __half22float2(g.h1);
  float2 f2 = __half22float2(g.h2), f3 = __half22float2(g.h3);
  acc[0] = fmaf(w, f0.x, acc[0]); acc[1] = fmaf(w, f0.y, acc[1]);
  acc[2] = fmaf(w, f1.x, acc[2]); acc[3] = fmaf(w, f1.y, acc[3]);
  acc[4] = fmaf(w, f2.x, acc[4]); acc[5] = fmaf(w, f2.y, acc[5]);
  acc[6] = fmaf(w, f3.x, acc[6]); acc[7] = fmaf(w, f3.y, acc[7]);
}

// ---------- GEMM + fused attention coefficients, 4 rows/thread, fp16 G out ----------
// inner loop blocked by 4 k-steps: float4 LDS reads for BOTH wl and hl.
template <int INC, int OUTC, int H>
__global__ __launch_bounds__(256) void gemm_k(const float* __restrict__ A,
                                              const float* __restrict__ W,
                                              const float* __restrict__ asrc,
                                              const float* __restrict__ adst,
                                              __half* __restrict__ G,
                                              float* __restrict__ als,
                                              float* __restrict__ ald, int nrows) {
  constexpr int TPR  = OUTC / 4;
  constexpr int RS   = 256 / TPR;
  constexpr int ROWS = RS * 4;
  __shared__ float wl[INC * OUTC];
  __shared__ float hl[ROWS * INC];
  for (int i = threadIdx.x * 4; i < INC * OUTC; i += 1024)
    *(float4*)&wl[i] = *(const float4*)&W[i];
  int r  = threadIdx.x / TPR;
  int c0 = (threadIdx.x % TPR) * 4;
  float4 sv = *(const float4*)&asrc[c0];
  float4 dv = *(const float4*)&adst[c0];
  for (int base = blockIdx.x * ROWS; base < nrows; base += gridDim.x * ROWS) {
    __syncthreads();
    int limit = min(ROWS, nrows - base) * INC;
    for (int i = threadIdx.x * 4; i < limit; i += 1024)
      *(float4*)&hl[i] = *(const float4*)&A[(size_t)base * INC + i];
    __syncthreads();
    float acc[4][4];
#pragma unroll
    for (int q = 0; q < 4; q++)
#pragma unroll
      for (int c = 0; c < 4; c++) acc[q][c] = 0.f;
#pragma unroll 2
    for (int kb = 0; kb < INC; kb += 4) {
      float4 wv0 = *(float4*)&wl[(kb + 0) * OUTC + c0];
      float4 wv1 = *(float4*)&wl[(kb + 1) * OUTC + c0];
      float4 wv2 = *(float4*)&wl[(kb + 2) * OUTC + c0];
      float4 wv3 = *(float4*)&wl[(kb + 3) * OUTC + c0];
#pragma unroll
      for (int q = 0; q < 4; q++) {
        float4 hv = *(float4*)&hl[(r + q * RS) * INC + kb];
        acc[q][0] = fmaf(hv.x, wv0.x, acc[q][0]);
        acc[q][1] = fmaf(hv.x, wv0.y, acc[q][1]);
        acc[q][2] = fmaf(hv.x, wv0.z, acc[q][2]);
        acc[q][3] = fmaf(hv.x, wv0.w, acc[q][3]);
        acc[q][0] = fmaf(hv.y, wv1.x, acc[q][0]);
        acc[q][1] = fmaf(hv.y, wv1.y, acc[q][1]);
        acc[q][2] = fmaf(hv.y, wv1.z, acc[q][2]);
        acc[q][3] = fmaf(hv.y, wv1.w, acc[q][3]);
        acc[q][0] = fmaf(hv.z, wv2.x, acc[q][0]);
        acc[q][1] = fmaf(hv.z, wv2.y, acc[q][1]);
        acc[q][2] = fmaf(hv.z, wv2.z, acc[q][2]);
        acc[q][3] = fmaf(hv.z, wv2.w, acc[q][3]);
        acc[q][0] = fmaf(hv.w, wv3.x, acc[q][0]);
        acc[q][1] = fmaf(hv.w, wv3.y, acc[q][1]);
        acc[q][2] = fmaf(hv.w, wv3.z, acc[q][2]);
        acc[q][3] = fmaf(hv.w, wv3.w, acc[q][3]);
      }
    }
    float ps[4], pd[4];
#pragma unroll
    for (int q = 0; q < 4; q++) {
      int rq = base + r + q * RS;
      if (rq < nrows) {
        half4v hv;
        hv.lo = __floats2half2_rn(acc[q][0], acc[q][1]);
        hv.hi = __floats2half2_rn(acc[q][2], acc[q][3]);
        *(half4v*)&G[(size_t)rq * OUTC + c0] = hv;
      }
      ps[q] = acc[q][0] * sv.x + acc[q][1] * sv.y + acc[q][2] * sv.z + acc[q][3] * sv.w;
      pd[q] = acc[q][0] * dv.x + acc[q][1] * dv.y + acc[q][2] * dv.z + acc[q][3] * dv.w;
    }
#pragma unroll
    for (int o = 1; o < 16; o <<= 1) {
#pragma unroll
      for (int q = 0; q < 4; q++) {
        ps[q] += __shfl_xor(ps[q], o);
        pd[q] += __shfl_xor(pd[q], o);
      }
    }
    if ((threadIdx.x & 15) == 0) {
      int head = c0 >> 6;
#pragma unroll
      for (int q = 0; q < 4; q++) {
        int rq = base + r + q * RS;
        if (rq < nrows) {
          als[(size_t)rq * H + head] = ps[q];
          ald[(size_t)rq * H + head] = pd[q];
        }
      }
    }
  }
}

// ---------- CSR build (XCD-local scatter) ----------
__global__ __launch_bounds__(256) void deg_k(const int* __restrict__ dst, int E_,
                                             int n, int* __restrict__ deg) {
  int g   = blockIdx.x & 7;
  int npg = (n + 7) / 8;
  int n0  = g * npg;
  int n1  = min(n0 + npg, n);
  int bg  = blockIdx.x >> 3;
  int nbg = gridDim.x >> 3;
  int ET  = E_ + n;
  for (int e = bg * 256 + threadIdx.x; e < ET; e += nbg * 256) {
    int dN = (e < E_) ? dst[e] : (e - E_);
    if (dN >= n0 && dN < n1) atomicAdd(&deg[dN], 1);
  }
}

__global__ __launch_bounds__(1024) void scan1_k(const int* __restrict__ deg,
                                                int* __restrict__ incl,
                                                int* __restrict__ bsum, int n) {
  __shared__ int sm[1024];
  int i = blockIdx.x * 1024 + threadIdx.x;
  int v = (i < n) ? deg[i] : 0;
  sm[threadIdx.x] = v;
  __syncthreads();
#pragma unroll
  for (int o = 1; o < 1024; o <<= 1) {
    int t = (threadIdx.x >= o) ? sm[threadIdx.x - o] : 0;
    __syncthreads();
    sm[threadIdx.x] += t;
    __syncthreads();
  }
  if (i < n) incl[i] = sm[threadIdx.x];
  if (threadIdx.x == 1023) bsum[blockIdx.x] = sm[1023];
}

__global__ void scan2_k(int* __restrict__ bsum, int nb) {
  int lane = threadIdx.x;
  int v = (lane < nb) ? bsum[lane] : 0;
#pragma unroll
  for (int o = 1; o < 64; o <<= 1) {
    int t = __shfl_up(v, o);
    if (lane >= o) v += t;
  }
  if (lane < nb) bsum[lane] = v;
}

__global__ void scan3_k(const int* __restrict__ incl, const int* __restrict__ bsum,
                        const int* __restrict__ deg, int* __restrict__ rowptr,
                        int* __restrict__ cursor, int n) {
  int i = blockIdx.x * blockDim.x + threadIdx.x;
  if (i < n) {
    int blk = i >> 10;
    int off = blk ? bsum[blk - 1] : 0;
    int r = incl[i] + off;
    rowptr[i + 1] = r;
    cursor[i] = r - deg[i];
  }
  if (i == 0) rowptr[0] = 0;
}

__global__ __launch_bounds__(256) void csr_fill_k(const int* __restrict__ src,
                                                  const int* __restrict__ dst, int E_,
                                                  int n, int* __restrict__ cursor,
                                                  uint16_t* __restrict__ csr_src) {
  int g   = blockIdx.x & 7;
  int npg = (n + 7) / 8;
  int n0  = g * npg;
  int n1  = min(n0 + npg, n);
  int bg  = blockIdx.x >> 3;
  int nbg = gridDim.x >> 3;
  int ET  = E_ + n;
  for (int e = bg * 256 + threadIdx.x; e < ET; e += nbg * 256) {
    int dN = (e < E_) ? dst[e] : (e - E_);
    if (dN >= n0 && dN < n1) {
      int sN  = (e < E_) ? src[e] : dN;
      int pos = atomicAdd(&cursor[dN], 1);
      csr_src[pos] = (uint16_t)sN;
    }
  }
}

// canonicalize: in-place rank-permutation sort of each dst segment by src id.
__global__ __launch_bounds__(256) void csr_canon_k(const int* __restrict__ rowptr,
                                                   uint16_t* __restrict__ csr, int n) {
  int l   = threadIdx.x & 31;
  int grp = (blockIdx.x * blockDim.x + threadIdx.x) >> 5;
  int ng  = (gridDim.x * blockDim.x) >> 5;
  for (int node = grp; node < n; node += ng) {
    int beg = rowptr[node];
    int deg = rowptr[node + 1] - beg;
    if (deg <= 1) continue;
    if (deg <= 128) {
      int iters = (deg + 31) >> 5;
      uint16_t v[4];
      int      rk[4];
#pragma unroll
      for (int m = 0; m < 4; m++) {
        if (m >= iters) break;
        int  i   = l + m * 32;
        bool act = i < deg;
        uint16_t vi = act ? csr[beg + i] : (uint16_t)0;
        int rank = 0;
        for (int j = 0; j < deg; j++) {
          uint16_t vj = csr[beg + j];
          rank += (int)((vj < vi) | ((vj == vi) & (j < i)));
        }
        v[m]  = vi;
        rk[m] = act ? rank : -1;
      }
#pragma unroll
      for (int m = 0; m < 4; m++) {
        if (m >= iters) break;
        if (rk[m] >= 0) csr[beg + rk[m]] = v[m];
      }
    } else if (l == 0) {
      for (int i = beg + 1; i < beg + deg; ++i) {
        uint16_t vv = csr[i];
        int j = i - 1;
        while (j >= beg && csr[j] > vv) { csr[j + 1] = csr[j]; --j; }
        csr[j + 1] = vv;
      }
    }
  }
}

// ---------- fused GAT aggregation (H=2): 32-lane groups, hoisted BN params ----------
__global__ __launch_bounds__(256) void gat_agg2_k(
    const int* __restrict__ rowptr, const uint16_t* __restrict__ csr_src,
    const float* __restrict__ als, const float* __restrict__ ald,
    const __half* __restrict__ G, const float* __restrict__ bias,
    const float* __restrict__ gamma, const float* __restrict__ beta,
    const float* __restrict__ mean, const float* __restrict__ var,
    float* __restrict__ out, int n) {
  int l   = threadIdx.x & 31;
  int grp = (blockIdx.x * blockDim.x + threadIdx.x) >> 5;
  int ng  = (gridDim.x * blockDim.x) >> 5;
  int ehi = l >> 4;
  int sub = l & 15;
  int cc  = sub * 8;
  bool hh = sub >= 8;
  // hoisted per-channel BN fold: out = relu(fma(acc, s, t))
  float s8[8], t8[8];
  {
    float4 bv0 = *(const float4*)&bias[cc],  bv1 = *(const float4*)&bias[cc + 4];
    float4 mv0 = *(const float4*)&mean[cc],  mv1 = *(const float4*)&mean[cc + 4];
    float4 vv0 = *(const float4*)&var[cc],   vv1 = *(const float4*)&var[cc + 4];
    float4 gv0 = *(const float4*)&gamma[cc], gv1 = *(const float4*)&gamma[cc + 4];
    float4 tv0 = *(const float4*)&beta[cc],  tv1 = *(const float4*)&beta[cc + 4];
    float bb[8] = {bv0.x, bv0.y, bv0.z, bv0.w, bv1.x, bv1.y, bv1.z, bv1.w};
    float mm[8] = {mv0.x, mv0.y, mv0.z, mv0.w, mv1.x, mv1.y, mv1.z, mv1.w};
    float vv[8] = {vv0.x, vv0.y, vv0.z, vv0.w, vv1.x, vv1.y, vv1.z, vv1.w};
    float gg[8] = {gv0.x, gv0.y, gv0.z, gv0.w, gv1.x, gv1.y, gv1.z, gv1.w};
    float tb[8] = {tv0.x, tv0.y, tv0.z, tv0.w, tv1.x, tv1.y, tv1.z, tv1.w};
#pragma unroll
    for (int k = 0; k < 8; k++) {
      s8[k] = gg[k] * rsqrtf(vv[k] + BN_EPS);
      t8[k] = (bb[k] - mm[k]) * s8[k] + tb[k];
    }
  }
  for (int node = grp; node < n; node += ng) {
    int beg = rowptr[node];
    int deg = rowptr[node + 1] - beg;
    float2 adp = *(const float2*)&ald[(size_t)node * 2];
    float accP[8], accQ[8];
#pragma unroll
    for (int k = 0; k < 8; k++) { accP[k] = 0.f; accQ[k] = 0.f; }
    if (deg <= 32) {
      int sl_ = 0;
      float p0 = 0.f, p1 = 0.f;
      if (l < deg) {
        sl_ = csr_src[beg + l];
        float2 ap = *(const float2*)&als[(size_t)sl_ * 2];
        float v0 = ap.x + adp.x, v1 = ap.y + adp.y;
        v0 = v0 > 0.f ? v0 : NEG_SLOPE * v0;
        v1 = v1 > 0.f ? v1 : NEG_SLOPE * v1;
        p0 = __expf(v0); p1 = __expf(v1);
      }
      float s0 = p0, s1 = p1;
#pragma unroll
      for (int o = 1; o < 32; o <<= 1) {
        s0 += __shfl_xor(s0, o, 32);
        s1 += __shfl_xor(s1, o, 32);
      }
      float a0 = p0 / (s0 + SM_EPS);
      float a1 = p1 / (s1 + SM_EPS);
      for (int i = 0; i < deg; i += 8) {
        int e0 = i + ehi, e1 = i + 2 + ehi, e2 = i + 4 + ehi, e3 = i + 6 + ehi;
        int sA = __shfl(sl_, e0, 32);
        int sB = __shfl(sl_, e1, 32);
        int sC = __shfl(sl_, e2, 32);
        int sD = __shfl(sl_, e3, 32);
        float wA0 = __shfl(a0, e0, 32), wA1 = __shfl(a1, e0, 32);
        float wB0 = __shfl(a0, e1, 32), wB1 = __shfl(a1, e1, 32);
        float wC0 = __shfl(a0, e2, 32), wC1 = __shfl(a1, e2, 32);
        float wD0 = __shfl(a0, e3, 32), wD1 = __shfl(a1, e3, 32);
        float wA = hh ? wA1 : wA0, wB = hh ? wB1 : wB0;
        float wC = hh ? wC1 : wC0, wD = hh ? wD1 : wD0;
        half8v gA = *(const half8v*)&G[(size_t)sA * 128 + cc];
        half8v gB = *(const half8v*)&G[(size_t)sB * 128 + cc];
        half8v gC = *(const half8v*)&G[(size_t)sC * 128 + cc];
        half8v gD = *(const half8v*)&G[(size_t)sD * 128 + cc];
        fma8(accP, gA, wA);
        fma8(accQ, gB, wB);
        fma8(accP, gC, wC);
        fma8(accQ, gD, wD);
      }
    } else {
      float s0 = 0.f, s1 = 0.f;
      for (int i = l; i < deg; i += 32) {
        int s = csr_src[beg + i];
        float2 ap = *(const float2*)&als[(size_t)s * 2];
        float v0 = ap.x + adp.x; v0 = v0 > 0.f ? v0 : NEG_SLOPE * v0;
        float v1 = ap.y + adp.y; v1 = v1 > 0.f ? v1 : NEG_SLOPE * v1;
        s0 += __expf(v0); s1 += __expf(v1);
      }
#pragma unroll
      for (int o = 1; o < 32; o <<= 1) {
        s0 += __shfl_xor(s0, o, 32);
        s1 += __shfl_xor(s1, o, 32);
      }
      float inv0 = 1.f / (s0 + SM_EPS);
      float inv1 = 1.f / (s1 + SM_EPS);
      for (int i = 0; i < deg; i += 2) {
        int  e   = i + ehi;
        bool act = e < deg;
        int  sE  = 0;
        float w  = 0.f;
        if (act) {
          sE = csr_src[beg + e];
          float2 ap = *(const float2*)&als[(size_t)sE * 2];
          float v0 = ap.x + adp.x; v0 = v0 > 0.f ? v0 : NEG_SLOPE * v0;
          float v1 = ap.y + adp.y; v1 = v1 > 0.f ? v1 : NEG_SLOPE * v1;
          w = hh ? (__expf(v1) * inv1) : (__expf(v0) * inv0);
        }
        half8v g = *(const half8v*)&G[(size_t)sE * 128 + cc];
        fma8(accP, g, w);
      }
    }
    float o8[8];
#pragma unroll
    for (int k = 0; k < 8; k++) {
      o8[k] = accP[k] + accQ[k];
      o8[k] += __shfl_xor(o8[k], 16, 32);
      o8[k] = fmaxf(fmaf(o8[k], s8[k], t8[k]), 0.f);
    }
    if (l < 16) {
      float4 u0 = make_float4(o8[0], o8[1], o8[2], o8[3]);
      float4 u1 = make_float4(o8[4], o8[5], o8[6], o8[7]);
      *(float4*)&out[(size_t)node * 128 + cc]     = u0;
      *(float4*)&out[(size_t)node * 128 + cc + 4] = u1;
    }
  }
}

// ---------- GAT aggregation (H=1, final layer): 32-lane groups, hoisted bias ----------
__global__ __launch_bounds__(256) void gat_agg1_k(
    const int* __restrict__ rowptr, const uint16_t* __restrict__ csr_src,
    const float* __restrict__ als, const float* __restrict__ ald,
    const __half* __restrict__ G, const float* __restrict__ bias,
    float* __restrict__ out, int n) {
  int l   = threadIdx.x & 31;
  int grp = (blockIdx.x * blockDim.x + threadIdx.x) >> 5;
  int ng  = (gridDim.x * blockDim.x) >> 5;
  int e8  = l >> 3;
  int sub = l & 7;
  int cc  = sub * 8;
  float b8[8];
  {
    float4 bv0 = *(const float4*)&bias[cc], bv1 = *(const float4*)&bias[cc + 4];
    b8[0] = bv0.x; b8[1] = bv0.y; b8[2] = bv0.z; b8[3] = bv0.w;
    b8[4] = bv1.x; b8[5] = bv1.y; b8[6] = bv1.z; b8[7] = bv1.w;
  }
  for (int node = grp; node < n; node += ng) {
    int beg = rowptr[node];
    int deg = rowptr[node + 1] - beg;
    float ad0 = ald[node];
    float accP[8], accQ[8];
#pragma unroll
    for (int k = 0; k < 8; k++) { accP[k] = 0.f; accQ[k] = 0.f; }
    if (deg <= 32) {
      int sl_ = 0;
      float p0 = 0.f;
      if (l < deg) {
        sl_ = csr_src[beg + l];
        float v0 = als[sl_] + ad0;
        v0 = v0 > 0.f ? v0 : NEG_SLOPE * v0;
        p0 = __expf(v0);
      }
      float s0 = p0;
#pragma unroll
      for (int o = 1; o < 32; o <<= 1) s0 += __shfl_xor(s0, o, 32);
      float a0 = p0 / (s0 + SM_EPS);
      for (int i = 0; i < deg; i += 16) {
        int e0 = i + e8, e1 = i + 4 + e8, e2 = i + 8 + e8, e3 = i + 12 + e8;
        int sA = __shfl(sl_, e0, 32);
        int sB = __shfl(sl_, e1, 32);
        int sC = __shfl(sl_, e2, 32);
        int sD = __shfl(sl_, e3, 32);
        float wA = __shfl(a0, e0, 32);
        float wB = __shfl(a0, e1, 32);
        float wC = __shfl(a0, e2, 32);
        float wD = __shfl(a0, e3, 32);
        half8v gA = *(const half8v*)&G[(size_t)sA * 64 + cc];
        half8v gB = *(const half8v*)&G[(size_t)sB * 64 + cc];
        half8v gC = *(const half8v*)&G[(size_t)sC * 64 + cc];
        half8v gD = *(const half8v*)&G[(size_t)sD * 64 + cc];
        fma8(accP, gA, wA);
        fma8(accQ, gB, wB);
        fma8(accP, gC, wC);
        fma8(accQ, gD, wD);
      }
    } else {
      float s0 = 0.f;
      for (int i = l; i < deg; i += 32) {
        int s = csr_src[beg + i];
        float v0 = als[s] + ad0; v0 = v0 > 0.f ? v0 : NEG_SLOPE * v0;
        s0 += __expf(v0);
      }
#pragma unroll
      for (int o = 1; o < 32; o <<= 1) s0 += __shfl_xor(s0, o, 32);
      float inv0 = 1.f / (s0 + SM_EPS);
      for (int i = 0; i < deg; i += 4) {
        int  e   = i + e8;
        bool act = e < deg;
        int  sE  = 0;
        float w  = 0.f;
        if (act) {
          sE = csr_src[beg + e];
          float v0 = als[sE] + ad0; v0 = v0 > 0.f ? v0 : NEG_SLOPE * v0;
          w = __expf(v0) * inv0;
        }
        half8v g = *(const half8v*)&G[(size_t)sE * 64 + cc];
        fma8(accP, g, w);
      }
    }
    float o8[8];
#pragma unroll
    for (int k = 0; k < 8; k++) {
      o8[k] = accP[k] + accQ[k];
      o8[k] += __shfl_xor(o8[k], 8, 32);
      o8[k] += __shfl_xor(o8[k], 16, 32);
      o8[k] += b8[k];
    }
    if (l < 8) {
      float4 u0 = make_float4(o8[0], o8[1], o8[2], o8[3]);
      float4 u1 = make_float4(o8[4], o8[5], o8[6], o8[7]);
      *(float4*)&out[(size_t)node * 64 + cc]     = u0;
      *(float4*)&out[(size_t)node * 64 + cc + 4] = u1;
    }
  }
}

// =======================================================================
extern "C" void kernel_launch(void* const* d_in, const int* in_sizes, int n_in,
                              void* d_out, int out_size, void* d_ws, size_t ws_size,
                              hipStream_t stream) {
  const float* x   = (const float*)d_in[0];
  const int*   ei  = (const int*)d_in[1];
  const float* W0  = (const float*)d_in[2];
  const float* as0 = (const float*)d_in[3];
  const float* ad0 = (const float*)d_in[4];
  const float* b0  = (const float*)d_in[5];
  const float* gm0 = (const float*)d_in[6];
  const float* bt0 = (const float*)d_in[7];
  const float* mu0 = (const float*)d_in[8];
  const float* vr0 = (const float*)d_in[9];
  const float* W1  = (const float*)d_in[10];
  const float* as1 = (const float*)d_in[11];
  const float* ad1 = (const float*)d_in[12];
  const float* b1  = (const float*)d_in[13];
  const float* gm1 = (const float*)d_in[14];
  const float* bt1 = (const float*)d_in[15];
  const float* mu1 = (const float*)d_in[16];
  const float* vr1 = (const float*)d_in[17];
  const float* W2  = (const float*)d_in[18];
  const float* as2 = (const float*)d_in[19];
  const float* ad2 = (const float*)d_in[20];
  const float* b2  = (const float*)d_in[21];

  int N  = in_sizes[0] / 128;
  int E  = in_sizes[1] / 2;
  int ET = E + N;
  const int* srcp = ei;
  const int* dstp = ei + E;

  char* w = (char*)d_ws;
  auto carve = [&](size_t bytes) {
    void* p = (void*)w;
    w += (bytes + 255) & ~(size_t)255;
    return p;
  };
  __half*   G      = (__half*)carve((size_t)N * 128 * 2);
  float*    Hb     = (float*)carve((size_t)N * 128 * 4);
  float*    ALS    = (float*)carve((size_t)N * 2 * 4);
  float*    ALD    = (float*)carve((size_t)N * 2 * 4);
  int*      DEG    = (int*)carve((size_t)N * 4);
  int*      INCL   = (int*)carve((size_t)N * 4);
  int*      BSUM   = (int*)carve((size_t)64 * 4);
  int*      ROWPTR = (int*)carve((size_t)(N + 1) * 4);
  int*      CURSOR = (int*)carve((size_t)N * 4);
  uint16_t* CSRSRC = (uint16_t*)carve((size_t)ET * 2);

  int cgrid = (N + 7) / 8;   // canon: 1 node per 32-lane group
  int agrid = 2048;          // agg: grid-stride, ~3 nodes per 32-lane group
  int nblk  = (N + 1023) / 1024;

  // ---- CSR build (graph shared by all 3 layers) ----
  hipMemsetAsync(DEG, 0, (size_t)N * 4, stream);
  deg_k<<<2048, 256, 0, stream>>>(dstp, E, N, DEG);
  scan1_k<<<nblk, 1024, 0, stream>>>(DEG, INCL, BSUM, N);
  scan2_k<<<1, 64, 0, stream>>>(BSUM, nblk);
  scan3_k<<<(N + 255) / 256, 256, 0, stream>>>(INCL, BSUM, DEG, ROWPTR, CURSOR, N);
  csr_fill_k<<<2048, 256, 0, stream>>>(srcp, dstp, E, N, CURSOR, CSRSRC);
  csr_canon_k<<<cgrid, 256, 0, stream>>>(ROWPTR, CSRSRC, N);

  // ---------------- layer 0 ----------------
  gemm_k<128, 128, 2><<<512, 256, 0, stream>>>(x, W0, as0, ad0, G, ALS, ALD, N);
  gat_agg2_k<<<agrid, 256, 0, stream>>>(ROWPTR, CSRSRC, ALS, ALD, G, b0, gm0, bt0,
                                        mu0, vr0, Hb, N);
  // ---------------- layer 1 ----------------
  gemm_k<128, 128, 2><<<512, 256, 0, stream>>>(Hb, W1, as1, ad1, G, ALS, ALD, N);
  gat_agg2_k<<<agrid, 256, 0, stream>>>(ROWPTR, CSRSRC, ALS, ALD, G, b1, gm1, bt1,
                                        mu1, vr1, Hb, N);
  // ---------------- layer 2 ----------------
  gemm_k<128, 64, 1><<<512, 256, 0, stream>>>(Hb, W2, as2, ad2, G, ALS, ALD, N);
  gat_agg1_k<<<agrid, 256, 0, stream>>>(ROWPTR, CSRSRC, ALS, ALD, G, b2,
                                        (float*)d_out, N);
}

// Round 16
// 264.098 us; speedup vs baseline: 1.2520x; 1.2050x over previous
//
#include <hip/hip_runtime.h>
#include <hip/hip_fp16.h>
#include <cstdint>

#define NEG_SLOPE 0.2f
#define SM_EPS 1e-16f
#define BN_EPS 1e-5f

struct alignas(8)  half4v { __half2 lo, hi; };
struct alignas(16) half8v { __half2 h0, h1, h2, h3; };

typedef _Float16 f16x8 __attribute__((ext_vector_type(8)));
typedef float    f32x4 __attribute__((ext_vector_type(4)));

__device__ __forceinline__ void fma8(float* acc, const half8v& g, float w) {
  float2 f0 = __half22float2(g.h0), f1 = __half22float2(g.h1);
  float2 f2 = __half22float2(g.h2), f3 = __half22float2(g.h3);
  acc[0] = fmaf(w, f0.x, acc[0]); acc[1] = fmaf(w, f0.y, acc[1]);
  acc[2] = fmaf(w, f1.x, acc[2]); acc[3] = fmaf(w, f1.y, acc[3]);
  acc[4] = fmaf(w, f2.x, acc[4]); acc[5] = fmaf(w, f2.y, acc[5]);
  acc[6] = fmaf(w, f3.x, acc[6]); acc[7] = fmaf(w, f3.y, acc[7]);
}

// ---------- pack W (fp32 [K=128][OUTC]) into MFMA B-fragment order, fp16 ----------
// P[(((ct*4+kt)*64+lane)*8+j)] = W[kt*32+(lane>>4)*8+j][ct*16+(lane&15)]
__global__ void packW_k(const float* __restrict__ W0, const float* __restrict__ W1,
                        const float* __restrict__ W2, _Float16* __restrict__ P0,
                        _Float16* __restrict__ P1, _Float16* __restrict__ P2) {
  int t = blockIdx.x * 256 + threadIdx.x;
  const float* W; _Float16* P; int OUTC, idx;
  if (t < 16384)      { W = W0; P = P0; OUTC = 128; idx = t; }
  else if (t < 32768) { W = W1; P = P1; OUTC = 128; idx = t - 16384; }
  else if (t < 40960) { W = W2; P = P2; OUTC = 64;  idx = t - 32768; }
  else return;
  int j = idx & 7, lane = (idx >> 3) & 63, kt = (idx >> 9) & 3, ct = idx >> 11;
  int k = kt * 32 + (lane >> 4) * 8 + j;
  int c = ct * 16 + (lane & 15);
  P[idx] = (_Float16)W[k * OUTC + c];
}

// ---------- MFMA GEMM + fused attention coefficients ----------
// A fp32 [n][128] converted to fp16 in-register; Wp packed fp16; G fp16 out.
template <int OUTC, int H>
__global__ __launch_bounds__(256) void gemm_mfma_k(
    const float* __restrict__ A, const _Float16* __restrict__ Wp,
    const float* __restrict__ asrc, const float* __restrict__ adst,
    __half* __restrict__ G, float* __restrict__ als, float* __restrict__ ald,
    int nrows) {
  constexpr int CT = OUTC / 16;
  int wid = threadIdx.x >> 6;   // wave 0..3 (16 rows each)
  int l   = threadIdx.x & 63;
  int r16 = l & 15;             // A-row / D-col within tile
  int kb  = l >> 4;             // k-block 0..3
  for (int base = blockIdx.x * 64 + wid * 16; base < nrows; base += gridDim.x * 64) {
    int arow = base + r16; if (arow >= nrows) arow = nrows - 1;  // clamped rows' D discarded
    const float* ap = &A[(size_t)arow * 128];
    f16x8 af[4];
#pragma unroll
    for (int kt = 0; kt < 4; kt++) {
      float4 x0 = *(const float4*)&ap[kt * 32 + kb * 8];
      float4 x1 = *(const float4*)&ap[kt * 32 + kb * 8 + 4];
      f16x8 v;
      v[0] = (_Float16)x0.x; v[1] = (_Float16)x0.y;
      v[2] = (_Float16)x0.z; v[3] = (_Float16)x0.w;
      v[4] = (_Float16)x1.x; v[5] = (_Float16)x1.y;
      v[6] = (_Float16)x1.z; v[7] = (_Float16)x1.w;
      af[kt] = v;
    }
    f32x4 acc[CT];
#pragma unroll
    for (int ct = 0; ct < CT; ct++) {
      f32x4 a = {0.f, 0.f, 0.f, 0.f};
#pragma unroll
      for (int kt = 0; kt < 4; kt++) {
        f16x8 bf = *(const f16x8*)&Wp[(size_t)(((ct * 4 + kt) * 64 + l)) * 8];
        a = __builtin_amdgcn_mfma_f32_16x16x32_f16(af[kt], bf, a, 0, 0, 0);
      }
      acc[ct] = a;
    }
    // D layout: col = ct*16 + r16, row = base + kb*4 + r
    float ps0[4] = {0, 0, 0, 0}, ps1[4] = {0, 0, 0, 0};
    float pd0[4] = {0, 0, 0, 0}, pd1[4] = {0, 0, 0, 0};
#pragma unroll
    for (int ct = 0; ct < CT; ct++) {
      int col = ct * 16 + r16;
      float as_ = asrc[col], ad_ = adst[col];
      bool h1 = (H == 2) && (col >= 64);
#pragma unroll
      for (int r = 0; r < 4; r++) {
        float v = acc[ct][r];
        int rowD = base + kb * 4 + r;
        if (rowD < nrows) G[(size_t)rowD * OUTC + col] = __float2half(v);
        if (h1) { ps1[r] = fmaf(v, as_, ps1[r]); pd1[r] = fmaf(v, ad_, pd1[r]); }
        else    { ps0[r] = fmaf(v, as_, ps0[r]); pd0[r] = fmaf(v, ad_, pd0[r]); }
      }
    }
#pragma unroll
    for (int o = 1; o < 16; o <<= 1) {
#pragma unroll
      for (int r = 0; r < 4; r++) {
        ps0[r] += __shfl_xor(ps0[r], o);
        pd0[r] += __shfl_xor(pd0[r], o);
        if (H == 2) {
          ps1[r] += __shfl_xor(ps1[r], o);
          pd1[r] += __shfl_xor(pd1[r], o);
        }
      }
    }
    if (r16 == 0) {
#pragma unroll
      for (int r = 0; r < 4; r++) {
        int rowD = base + kb * 4 + r;
        if (rowD < nrows) {
          if (H == 2) {
            als[(size_t)rowD * 2]     = ps0[r];
            als[(size_t)rowD * 2 + 1] = ps1[r];
            ald[(size_t)rowD * 2]     = pd0[r];
            ald[(size_t)rowD * 2 + 1] = pd1[r];
          } else {
            als[rowD] = ps0[r];
            ald[rowD] = pd0[r];
          }
        }
      }
    }
  }
}

// ---------- CSR build (XCD-local scatter) ----------
__global__ __launch_bounds__(256) void deg_k(const int* __restrict__ dst, int E_,
                                             int n, int* __restrict__ deg) {
  int g   = blockIdx.x & 7;
  int npg = (n + 7) / 8;
  int n0  = g * npg;
  int n1  = min(n0 + npg, n);
  int bg  = blockIdx.x >> 3;
  int nbg = gridDim.x >> 3;
  int ET  = E_ + n;
  for (int e = bg * 256 + threadIdx.x; e < ET; e += nbg * 256) {
    int dN = (e < E_) ? dst[e] : (e - E_);
    if (dN >= n0 && dN < n1) atomicAdd(&deg[dN], 1);
  }
}

__global__ __launch_bounds__(1024) void scan1_k(const int* __restrict__ deg,
                                                int* __restrict__ incl,
                                                int* __restrict__ bsum, int n) {
  __shared__ int sm[1024];
  int i = blockIdx.x * 1024 + threadIdx.x;
  int v = (i < n) ? deg[i] : 0;
  sm[threadIdx.x] = v;
  __syncthreads();
#pragma unroll
  for (int o = 1; o < 1024; o <<= 1) {
    int t = (threadIdx.x >= o) ? sm[threadIdx.x - o] : 0;
    __syncthreads();
    sm[threadIdx.x] += t;
    __syncthreads();
  }
  if (i < n) incl[i] = sm[threadIdx.x];
  if (threadIdx.x == 1023) bsum[blockIdx.x] = sm[1023];
}

__global__ void scan2_k(int* __restrict__ bsum, int nb) {
  int lane = threadIdx.x;
  int v = (lane < nb) ? bsum[lane] : 0;
#pragma unroll
  for (int o = 1; o < 64; o <<= 1) {
    int t = __shfl_up(v, o);
    if (lane >= o) v += t;
  }
  if (lane < nb) bsum[lane] = v;
}

__global__ void scan3_k(const int* __restrict__ incl, const int* __restrict__ bsum,
                        const int* __restrict__ deg, int* __restrict__ rowptr,
                        int* __restrict__ cursor, int n) {
  int i = blockIdx.x * blockDim.x + threadIdx.x;
  if (i < n) {
    int blk = i >> 10;
    int off = blk ? bsum[blk - 1] : 0;
    int r = incl[i] + off;
    rowptr[i + 1] = r;
    cursor[i] = r - deg[i];
  }
  if (i == 0) rowptr[0] = 0;
}

__global__ __launch_bounds__(256) void csr_fill_k(const int* __restrict__ src,
                                                  const int* __restrict__ dst, int E_,
                                                  int n, int* __restrict__ cursor,
                                                  uint16_t* __restrict__ csr_src) {
  int g   = blockIdx.x & 7;
  int npg = (n + 7) / 8;
  int n0  = g * npg;
  int n1  = min(n0 + npg, n);
  int bg  = blockIdx.x >> 3;
  int nbg = gridDim.x >> 3;
  int ET  = E_ + n;
  for (int e = bg * 256 + threadIdx.x; e < ET; e += nbg * 256) {
    int dN = (e < E_) ? dst[e] : (e - E_);
    if (dN >= n0 && dN < n1) {
      int sN  = (e < E_) ? src[e] : dN;
      int pos = atomicAdd(&cursor[dN], 1);
      csr_src[pos] = (uint16_t)sN;
    }
  }
}

// canonicalize: in-place rank-permutation sort of each dst segment by src id.
__global__ __launch_bounds__(256) void csr_canon_k(const int* __restrict__ rowptr,
                                                   uint16_t* __restrict__ csr, int n) {
  int l   = threadIdx.x & 31;
  int grp = (blockIdx.x * blockDim.x + threadIdx.x) >> 5;
  int ng  = (gridDim.x * blockDim.x) >> 5;
  for (int node = grp; node < n; node += ng) {
    int beg = rowptr[node];
    int deg = rowptr[node + 1] - beg;
    if (deg <= 1) continue;
    if (deg <= 128) {
      int iters = (deg + 31) >> 5;
      uint16_t v[4];
      int      rk[4];
#pragma unroll
      for (int m = 0; m < 4; m++) {
        if (m >= iters) break;
        int  i   = l + m * 32;
        bool act = i < deg;
        uint16_t vi = act ? csr[beg + i] : (uint16_t)0;
        int rank = 0;
        for (int j = 0; j < deg; j++) {
          uint16_t vj = csr[beg + j];
          rank += (int)((vj < vi) | ((vj == vi) & (j < i)));
        }
        v[m]  = vi;
        rk[m] = act ? rank : -1;
      }
#pragma unroll
      for (int m = 0; m < 4; m++) {
        if (m >= iters) break;
        if (rk[m] >= 0) csr[beg + rk[m]] = v[m];
      }
    } else if (l == 0) {
      for (int i = beg + 1; i < beg + deg; ++i) {
        uint16_t vv = csr[i];
        int j = i - 1;
        while (j >= beg && csr[j] > vv) { csr[j + 1] = csr[j]; --j; }
        csr[j + 1] = vv;
      }
    }
  }
}

// ---------- fused GAT aggregation (H=2): 32-lane groups, 4 row-loads in flight ----------
__global__ __launch_bounds__(256) void gat_agg2_k(
    const int* __restrict__ rowptr, const uint16_t* __restrict__ csr_src,
    const float* __restrict__ als, const float* __restrict__ ald,
    const __half* __restrict__ G, const float* __restrict__ bias,
    const float* __restrict__ gamma, const float* __restrict__ beta,
    const float* __restrict__ mean, const float* __restrict__ var,
    float* __restrict__ out, int n) {
  int l   = threadIdx.x & 31;
  int grp = (blockIdx.x * blockDim.x + threadIdx.x) >> 5;
  int ng  = (gridDim.x * blockDim.x) >> 5;
  int ehi = l >> 4;
  int sub = l & 15;
  int cc  = sub * 8;
  bool hh = sub >= 8;
  for (int node = grp; node < n; node += ng) {
    int beg = rowptr[node];
    int deg = rowptr[node + 1] - beg;
    float2 adp = *(const float2*)&ald[(size_t)node * 2];
    float accP[8], accQ[8];
#pragma unroll
    for (int k = 0; k < 8; k++) { accP[k] = 0.f; accQ[k] = 0.f; }
    if (deg <= 32) {
      int sl_ = 0;
      float p0 = 0.f, p1 = 0.f;
      if (l < deg) {
        sl_ = csr_src[beg + l];
        float2 ap = *(const float2*)&als[(size_t)sl_ * 2];
        float v0 = ap.x + adp.x, v1 = ap.y + adp.y;
        v0 = v0 > 0.f ? v0 : NEG_SLOPE * v0;
        v1 = v1 > 0.f ? v1 : NEG_SLOPE * v1;
        p0 = __expf(v0); p1 = __expf(v1);
      }
      float s0 = p0, s1 = p1;
#pragma unroll
      for (int o = 1; o < 32; o <<= 1) {
        s0 += __shfl_xor(s0, o, 32);
        s1 += __shfl_xor(s1, o, 32);
      }
      float a0 = p0 / (s0 + SM_EPS);
      float a1 = p1 / (s1 + SM_EPS);
      for (int i = 0; i < deg; i += 8) {
        int e0 = i + ehi, e1 = i + 2 + ehi, e2 = i + 4 + ehi, e3 = i + 6 + ehi;
        int sA = __shfl(sl_, e0, 32);
        int sB = __shfl(sl_, e1, 32);
        int sC = __shfl(sl_, e2, 32);
        int sD = __shfl(sl_, e3, 32);
        float wA0 = __shfl(a0, e0, 32), wA1 = __shfl(a1, e0, 32);
        float wB0 = __shfl(a0, e1, 32), wB1 = __shfl(a1, e1, 32);
        float wC0 = __shfl(a0, e2, 32), wC1 = __shfl(a1, e2, 32);
        float wD0 = __shfl(a0, e3, 32), wD1 = __shfl(a1, e3, 32);
        float wA = hh ? wA1 : wA0, wB = hh ? wB1 : wB0;
        float wC = hh ? wC1 : wC0, wD = hh ? wD1 : wD0;
        half8v gA = *(const half8v*)&G[(size_t)sA * 128 + cc];
        half8v gB = *(const half8v*)&G[(size_t)sB * 128 + cc];
        half8v gC = *(const half8v*)&G[(size_t)sC * 128 + cc];
        half8v gD = *(const half8v*)&G[(size_t)sD * 128 + cc];
        fma8(accP, gA, wA);
        fma8(accQ, gB, wB);
        fma8(accP, gC, wC);
        fma8(accQ, gD, wD);
      }
    } else {
      float s0 = 0.f, s1 = 0.f;
      for (int i = l; i < deg; i += 32) {
        int s = csr_src[beg + i];
        float2 ap = *(const float2*)&als[(size_t)s * 2];
        float v0 = ap.x + adp.x; v0 = v0 > 0.f ? v0 : NEG_SLOPE * v0;
        float v1 = ap.y + adp.y; v1 = v1 > 0.f ? v1 : NEG_SLOPE * v1;
        s0 += __expf(v0); s1 += __expf(v1);
      }
#pragma unroll
      for (int o = 1; o < 32; o <<= 1) {
        s0 += __shfl_xor(s0, o, 32);
        s1 += __shfl_xor(s1, o, 32);
      }
      float inv0 = 1.f / (s0 + SM_EPS);
      float inv1 = 1.f / (s1 + SM_EPS);
      for (int i = 0; i < deg; i += 2) {
        int  e   = i + ehi;
        bool act = e < deg;
        int  sE  = 0;
        float w  = 0.f;
        if (act) {
          sE = csr_src[beg + e];
          float2 ap = *(const float2*)&als[(size_t)sE * 2];
          float v0 = ap.x + adp.x; v0 = v0 > 0.f ? v0 : NEG_SLOPE * v0;
          float v1 = ap.y + adp.y; v1 = v1 > 0.f ? v1 : NEG_SLOPE * v1;
          w = hh ? (__expf(v1) * inv1) : (__expf(v0) * inv0);
        }
        half8v g = *(const half8v*)&G[(size_t)sE * 128 + cc];
        fma8(accP, g, w);
      }
    }
    float o8[8];
#pragma unroll
    for (int k = 0; k < 8; k++) {
      o8[k] = accP[k] + accQ[k];
      o8[k] += __shfl_xor(o8[k], 16, 32);
    }
    if (l < 16) {
      float4 bv0 = *(const float4*)&bias[cc],  bv1 = *(const float4*)&bias[cc + 4];
      float4 mv0 = *(const float4*)&mean[cc],  mv1 = *(const float4*)&mean[cc + 4];
      float4 vv0 = *(const float4*)&var[cc],   vv1 = *(const float4*)&var[cc + 4];
      float4 gv0 = *(const float4*)&gamma[cc], gv1 = *(const float4*)&gamma[cc + 4];
      float4 tv0 = *(const float4*)&beta[cc],  tv1 = *(const float4*)&beta[cc + 4];
      float4 u0, u1;
      u0.x = fmaxf((o8[0] + bv0.x - mv0.x) * rsqrtf(vv0.x + BN_EPS) * gv0.x + tv0.x, 0.f);
      u0.y = fmaxf((o8[1] + bv0.y - mv0.y) * rsqrtf(vv0.y + BN_EPS) * gv0.y + tv0.y, 0.f);
      u0.z = fmaxf((o8[2] + bv0.z - mv0.z) * rsqrtf(vv0.z + BN_EPS) * gv0.z + tv0.z, 0.f);
      u0.w = fmaxf((o8[3] + bv0.w - mv0.w) * rsqrtf(vv0.w + BN_EPS) * gv0.w + tv0.w, 0.f);
      u1.x = fmaxf((o8[4] + bv1.x - mv1.x) * rsqrtf(vv1.x + BN_EPS) * gv1.x + tv1.x, 0.f);
      u1.y = fmaxf((o8[5] + bv1.y - mv1.y) * rsqrtf(vv1.y + BN_EPS) * gv1.y + tv1.y, 0.f);
      u1.z = fmaxf((o8[6] + bv1.z - mv1.z) * rsqrtf(vv1.z + BN_EPS) * gv1.z + tv1.z, 0.f);
      u1.w = fmaxf((o8[7] + bv1.w - mv1.w) * rsqrtf(vv1.w + BN_EPS) * gv1.w + tv1.w, 0.f);
      *(float4*)&out[(size_t)node * 128 + cc]     = u0;
      *(float4*)&out[(size_t)node * 128 + cc + 4] = u1;
    }
  }
}

// ---------- GAT aggregation (H=1): 32-lane groups, 4 row-loads in flight ----------
__global__ __launch_bounds__(256) void gat_agg1_k(
    const int* __restrict__ rowptr, const uint16_t* __restrict__ csr_src,
    const float* __restrict__ als, const float* __restrict__ ald,
    const __half* __restrict__ G, const float* __restrict__ bias,
    float* __restrict__ out, int n) {
  int l   = threadIdx.x & 31;
  int grp = (blockIdx.x * blockDim.x + threadIdx.x) >> 5;
  int ng  = (gridDim.x * blockDim.x) >> 5;
  int e8  = l >> 3;
  int sub = l & 7;
  int cc  = sub * 8;
  for (int node = grp; node < n; node += ng) {
    int beg = rowptr[node];
    int deg = rowptr[node + 1] - beg;
    float ad0 = ald[node];
    float accP[8], accQ[8];
#pragma unroll
    for (int k = 0; k < 8; k++) { accP[k] = 0.f; accQ[k] = 0.f; }
    if (deg <= 32) {
      int sl_ = 0;
      float p0 = 0.f;
      if (l < deg) {
        sl_ = csr_src[beg + l];
        float v0 = als[sl_] + ad0;
        v0 = v0 > 0.f ? v0 : NEG_SLOPE * v0;
        p0 = __expf(v0);
      }
      float s0 = p0;
#pragma unroll
      for (int o = 1; o < 32; o <<= 1) s0 += __shfl_xor(s0, o, 32);
      float a0 = p0 / (s0 + SM_EPS);
      for (int i = 0; i < deg; i += 16) {
        int e0 = i + e8, e1 = i + 4 + e8, e2 = i + 8 + e8, e3 = i + 12 + e8;
        int sA = __shfl(sl_, e0, 32);
        int sB = __shfl(sl_, e1, 32);
        int sC = __shfl(sl_, e2, 32);
        int sD = __shfl(sl_, e3, 32);
        float wA = __shfl(a0, e0, 32);
        float wB = __shfl(a0, e1, 32);
        float wC = __shfl(a0, e2, 32);
        float wD = __shfl(a0, e3, 32);
        half8v gA = *(const half8v*)&G[(size_t)sA * 64 + cc];
        half8v gB = *(const half8v*)&G[(size_t)sB * 64 + cc];
        half8v gC = *(const half8v*)&G[(size_t)sC * 64 + cc];
        half8v gD = *(const half8v*)&G[(size_t)sD * 64 + cc];
        fma8(accP, gA, wA);
        fma8(accQ, gB, wB);
        fma8(accP, gC, wC);
        fma8(accQ, gD, wD);
      }
    } else {
      float s0 = 0.f;
      for (int i = l; i < deg; i += 32) {
        int s = csr_src[beg + i];
        float v0 = als[s] + ad0; v0 = v0 > 0.f ? v0 : NEG_SLOPE * v0;
        s0 += __expf(v0);
      }
#pragma unroll
      for (int o = 1; o < 32; o <<= 1) s0 += __shfl_xor(s0, o, 32);
      float inv0 = 1.f / (s0 + SM_EPS);
      for (int i = 0; i < deg; i += 4) {
        int  e   = i + e8;
        bool act = e < deg;
        int  sE  = 0;
        float w  = 0.f;
        if (act) {
          sE = csr_src[beg + e];
          float v0 = als[sE] + ad0; v0 = v0 > 0.f ? v0 : NEG_SLOPE * v0;
          w = __expf(v0) * inv0;
        }
        half8v g = *(const half8v*)&G[(size_t)sE * 64 + cc];
        fma8(accP, g, w);
      }
    }
    float o8[8];
#pragma unroll
    for (int k = 0; k < 8; k++) {
      o8[k] = accP[k] + accQ[k];
      o8[k] += __shfl_xor(o8[k], 8, 32);
      o8[k] += __shfl_xor(o8[k], 16, 32);
    }
    if (l < 8) {
      float4 bv0 = *(const float4*)&bias[cc], bv1 = *(const float4*)&bias[cc + 4];
      float4 u0 = make_float4(o8[0] + bv0.x, o8[1] + bv0.y, o8[2] + bv0.z, o8[3] + bv0.w);
      float4 u1 = make_float4(o8[4] + bv1.x, o8[5] + bv1.y, o8[6] + bv1.z, o8[7] + bv1.w);
      *(float4*)&out[(size_t)node * 64 + cc]     = u0;
      *(float4*)&out[(size_t)node * 64 + cc + 4] = u1;
    }
  }
}

// =======================================================================
extern "C" void kernel_launch(void* const* d_in, const int* in_sizes, int n_in,
                              void* d_out, int out_size, void* d_ws, size_t ws_size,
                              hipStream_t stream) {
  const float* x   = (const float*)d_in[0];
  const int*   ei  = (const int*)d_in[1];
  const float* W0  = (const float*)d_in[2];
  const float* as0 = (const float*)d_in[3];
  const float* ad0 = (const float*)d_in[4];
  const float* b0  = (const float*)d_in[5];
  const float* gm0 = (const float*)d_in[6];
  const float* bt0 = (const float*)d_in[7];
  const float* mu0 = (const float*)d_in[8];
  const float* vr0 = (const float*)d_in[9];
  const float* W1  = (const float*)d_in[10];
  const float* as1 = (const float*)d_in[11];
  const float* ad1 = (const float*)d_in[12];
  const float* b1  = (const float*)d_in[13];
  const float* gm1 = (const float*)d_in[14];
  const float* bt1 = (const float*)d_in[15];
  const float* mu1 = (const float*)d_in[16];
  const float* vr1 = (const float*)d_in[17];
  const float* W2  = (const float*)d_in[18];
  const float* as2 = (const float*)d_in[19];
  const float* ad2 = (const float*)d_in[20];
  const float* b2  = (const float*)d_in[21];

  int N  = in_sizes[0] / 128;
  int E  = in_sizes[1] / 2;
  int ET = E + N;
  const int* srcp = ei;
  const int* dstp = ei + E;

  char* w = (char*)d_ws;
  auto carve = [&](size_t bytes) {
    void* p = (void*)w;
    w += (bytes + 255) & ~(size_t)255;
    return p;
  };
  __half*    G      = (__half*)carve((size_t)N * 128 * 2);
  float*     Hb     = (float*)carve((size_t)N * 128 * 4);
  float*     ALS    = (float*)carve((size_t)N * 2 * 4);
  float*     ALD    = (float*)carve((size_t)N * 2 * 4);
  int*       DEG    = (int*)carve((size_t)N * 4);
  int*       INCL   = (int*)carve((size_t)N * 4);
  int*       BSUM   = (int*)carve((size_t)64 * 4);
  int*       ROWPTR = (int*)carve((size_t)(N + 1) * 4);
  int*       CURSOR = (int*)carve((size_t)N * 4);
  uint16_t*  CSRSRC = (uint16_t*)carve((size_t)ET * 2);
  _Float16*  WP0    = (_Float16*)carve(16384 * 2);
  _Float16*  WP1    = (_Float16*)carve(16384 * 2);
  _Float16*  WP2    = (_Float16*)carve(8192 * 2);

  int cgrid = (N + 7) / 8;    // canon: 1 node per 32-lane group
  int agrid = (N + 7) / 8;    // agg: 1 node per 32-lane group (R12 config)
  int ggrid = (N + 63) / 64;  // mfma gemm: 64 rows per block
  int nblk  = (N + 1023) / 1024;

  // ---- weight pack + CSR build (graph shared by all 3 layers) ----
  packW_k<<<160, 256, 0, stream>>>(W0, W1, W2, WP0, WP1, WP2);
  hipMemsetAsync(DEG, 0, (size_t)N * 4, stream);
  deg_k<<<2048, 256, 0, stream>>>(dstp, E, N, DEG);
  scan1_k<<<nblk, 1024, 0, stream>>>(DEG, INCL, BSUM, N);
  scan2_k<<<1, 64, 0, stream>>>(BSUM, nblk);
  scan3_k<<<(N + 255) / 256, 256, 0, stream>>>(INCL, BSUM, DEG, ROWPTR, CURSOR, N);
  csr_fill_k<<<2048, 256, 0, stream>>>(srcp, dstp, E, N, CURSOR, CSRSRC);
  csr_canon_k<<<cgrid, 256, 0, stream>>>(ROWPTR, CSRSRC, N);

  // ---------------- layer 0 ----------------
  gemm_mfma_k<128, 2><<<ggrid, 256, 0, stream>>>(x, WP0, as0, ad0, G, ALS, ALD, N);
  gat_agg2_k<<<agrid, 256, 0, stream>>>(ROWPTR, CSRSRC, ALS, ALD, G, b0, gm0, bt0,
                                        mu0, vr0, Hb, N);
  // ---------------- layer 1 ----------------
  gemm_mfma_k<128, 2><<<ggrid, 256, 0, stream>>>(Hb, WP1, as1, ad1, G, ALS, ALD, N);
  gat_agg2_k<<<agrid, 256, 0, stream>>>(ROWPTR, CSRSRC, ALS, ALD, G, b1, gm1, bt1,
                                        mu1, vr1, Hb, N);
  // ---------------- layer 2 ----------------
  gemm_mfma_k<64, 1><<<ggrid, 256, 0, stream>>>(Hb, WP2, as2, ad2, G, ALS, ALD, N);
  gat_agg1_k<<<agrid, 256, 0, stream>>>(ROWPTR, CSRSRC, ALS, ALD, G, b2,
                                        (float*)d_out, N);
}